// Round 5
// baseline (781.829 us; speedup 1.0000x reference)
//
#include <hip/hip_runtime.h>
#include <hip/hip_bf16.h>

typedef __attribute__((ext_vector_type(8))) short  s16x8;
typedef __attribute__((ext_vector_type(4))) float  f32x4;

constexpr int EMB  = 16;
constexpr int LAT  = 8;
constexpr int EDIM = 32;
constexpr int HID  = 64;

constexpr int SCAN_BLK   = 256;
constexpr int SCAN_ITEMS = 4;
constexpr int SCAN_TILE  = SCAN_BLK * SCAN_ITEMS;  // 1024

__device__ __forceinline__ short f2b(float f) {
  __hip_bfloat16 h = __float2bfloat16(f);
  return __builtin_bit_cast(short, h);
}
__device__ __forceinline__ float asf(unsigned int u) { return __builtin_bit_cast(float, u); }

// ---------------------------------------------------------------------------
// Prep (all bf16):
//  W1c  [64 hid][32 k]  = ew_W1^T                       (GEMM1' A-operand)
//  W2p  GEMM2' A-fragments with k-map g(kt,lh,j)=(kt*2+(j>>2))*16+lh*4+(j&3)
//       and column permutation pi: tile-row r, tile ct2 ->
//       i = 2*ct2 + ((r>>1)&1),  o = 2*(r>>2) + (r&1)   (i*8+o = W2 column)
//  b2p  [ct2*16 + r] = bf16(b2[i*8+o])   (K-extension bias values)
//  dW1c [64 hid][16 k] = dec_W1^T
//  dW2p dec GEMM2' A-fragments, identity column map (col = ct2*16 + r)
// ---------------------------------------------------------------------------
__global__ void prep_kernel(const float* __restrict__ W1, const float* __restrict__ W2,
                            const float* __restrict__ b2,
                            const float* __restrict__ dW1, const float* __restrict__ dW2,
                            short* __restrict__ W1c, short* __restrict__ W2p,
                            short* __restrict__ b2p,
                            short* __restrict__ dW1c, short* __restrict__ dW2p) {
  int t = blockIdx.x * blockDim.x + threadIdx.x;
  if (t < 64 * 32) { int c = t / 32, k = t % 32; W1c[t] = f2b(W1[k * 64 + c]); }
  if (t < 8192) {
    int ct2 = t >> 10, kt = (t >> 9) & 1, lh = (t >> 7) & 3, r = (t >> 3) & 15, j = t & 7;
    int k = (kt * 2 + (j >> 2)) * 16 + lh * 4 + (j & 3);
    int i = 2 * ct2 + ((r >> 1) & 1);
    int o = 2 * (r >> 2) + (r & 1);
    W2p[t] = f2b(W2[k * 128 + i * 8 + o]);
  }
  if (t < 128) {
    int ct2 = t >> 4, r = t & 15;
    int i = 2 * ct2 + ((r >> 1) & 1);
    int o = 2 * (r >> 2) + (r & 1);
    b2p[t] = f2b(b2[i * 8 + o]);
  }
  if (t < 64 * 16) { int c = t / 16, k = t % 16; dW1c[t] = f2b(dW1[k * 64 + c]); }
  if (t < 2048) {
    int ct2 = t >> 10, kt = (t >> 9) & 1, lh = (t >> 7) & 3, r = (t >> 3) & 15, j = t & 7;
    int k = (kt * 2 + (j >> 2)) * 16 + lh * 4 + (j & 3);
    dW2p[t] = f2b(dW2[k * 32 + ct2 * 16 + r]);
  }
}

// ---------------------------------------------------------------------------
// CSR build: histogram + exclusive scan + edge-id fill
// ---------------------------------------------------------------------------
__global__ __launch_bounds__(256) void hist_kernel(const int* __restrict__ ei,
                                                   int* __restrict__ deg, int E) {
  int e = blockIdx.x * blockDim.x + threadIdx.x;
  if (e < E) atomicAdd(&deg[ei[E + e]], 1);
}

__global__ __launch_bounds__(SCAN_BLK) void scan1_kernel(
    const int* __restrict__ deg, int* __restrict__ loc,
    int* __restrict__ bsum, int N) {
  __shared__ int sh[SCAN_BLK];
  int tid  = threadIdx.x;
  int base = blockIdx.x * SCAN_TILE + tid * SCAN_ITEMS;
  int v[SCAN_ITEMS];
  int s = 0;
#pragma unroll
  for (int j = 0; j < SCAN_ITEMS; j++) {
    v[j] = (base + j < N) ? deg[base + j] : 0;
    s += v[j];
  }
  sh[tid] = s;
  __syncthreads();
  for (int off = 1; off < SCAN_BLK; off <<= 1) {
    int t = (tid >= off) ? sh[tid - off] : 0;
    __syncthreads();
    sh[tid] += t;
    __syncthreads();
  }
  int p = sh[tid] - s;
#pragma unroll
  for (int j = 0; j < SCAN_ITEMS; j++) {
    if (base + j < N) loc[base + j] = p;
    p += v[j];
  }
  if (tid == SCAN_BLK - 1) bsum[blockIdx.x] = sh[tid];
}

__global__ __launch_bounds__(SCAN_BLK) void scan2_kernel(int* __restrict__ bsum, int NB) {
  __shared__ int sh[SCAN_BLK];
  int tid  = threadIdx.x;
  int base = tid * SCAN_ITEMS;
  int v[SCAN_ITEMS];
  int s = 0;
#pragma unroll
  for (int j = 0; j < SCAN_ITEMS; j++) {
    v[j] = (base + j < NB) ? bsum[base + j] : 0;
    s += v[j];
  }
  sh[tid] = s;
  __syncthreads();
  for (int off = 1; off < SCAN_BLK; off <<= 1) {
    int t = (tid >= off) ? sh[tid - off] : 0;
    __syncthreads();
    sh[tid] += t;
    __syncthreads();
  }
  int p = sh[tid] - s;
#pragma unroll
  for (int j = 0; j < SCAN_ITEMS; j++) {
    if (base + j < NB) bsum[base + j] = p;
    p += v[j];
  }
}

__global__ __launch_bounds__(256) void scan3_kernel(
    const int* __restrict__ loc, const int* __restrict__ bsum,
    int* __restrict__ offs, int* __restrict__ cursor, int N) {
  int i = blockIdx.x * blockDim.x + threadIdx.x;
  if (i < N) {
    int v = loc[i] + bsum[i / SCAN_TILE];
    offs[i] = v;
    cursor[i] = v;
  }
}

__global__ __launch_bounds__(256) void fill_kernel(const int* __restrict__ ei,
                                                   int* __restrict__ cursor,
                                                   int* __restrict__ eid, int E) {
  int e = blockIdx.x * blockDim.x + threadIdx.x;
  if (e < E) {
    int pos = atomicAdd(&cursor[ei[E + e]], 1);
    eid[pos] = e;
  }
}

// ---------------------------------------------------------------------------
// Encoder: zero LDS, zero atomics, zero barriers. Per wave: 64 edges, 4 tiles.
// GEMM1' (transposed): lane(ll,lh) -> H[edge=ll][hid=ct*16+lh*4+reg]
// GEMM2' (transposed, pi-permuted cols, K-ext bias):
//   lane(ll,lh) c2[reg] = (G+b2)[i=2ct2+(reg>>1)][o=2lh+(reg&1)] of edge=ll
// Epilogue: q_o = sum_i xe_i * c2  with xe via 8 bf16-packed bpermutes/tile,
// full i-sum lane-local; coalesced float2 store to ms in EDGE order.
// ---------------------------------------------------------------------------
__global__ __launch_bounds__(256, 4) void enc_mfma_kernel(
    const int* __restrict__ ei, const float* __restrict__ attr,
    const float* __restrict__ emb,
    const short* __restrict__ W1c, const float* __restrict__ b1,
    const short* __restrict__ W2p, const short* __restrict__ b2p,
    float* __restrict__ ms, int E) {
  const int tid = threadIdx.x;
  const int w = tid >> 6, l = tid & 63;
  const int lh = l >> 4, ll = l & 15;
  const int ebase = blockIdx.x * 256 + w * 64;

  // phase 0: gather src embedding for this lane's edge, pack to bf16 pairs
  unsigned int xqp[8];
  {
    int ec = min(ebase + l, E - 1);
    int src = ei[ec];
    const float4* er = reinterpret_cast<const float4*>(emb) + (size_t)src * 4;
    float4 v0 = er[0], v1 = er[1], v2 = er[2], v3 = er[3];
    float xf[16] = {v0.x, v0.y, v0.z, v0.w, v1.x, v1.y, v1.z, v1.w,
                    v2.x, v2.y, v2.z, v2.w, v3.x, v3.y, v3.z, v3.w};
#pragma unroll
    for (int c = 0; c < 8; c++)
      xqp[c] = ((unsigned int)(unsigned short)f2b(xf[2 * c + 1]) << 16) |
               (unsigned int)(unsigned short)f2b(xf[2 * c]);
  }

  // weights (VGPR/AGPR resident)
  s16x8 b1f[4];
#pragma unroll
  for (int ct = 0; ct < 4; ct++)
    b1f[ct] = *reinterpret_cast<const s16x8*>(W1c + (ct * 16 + ll) * 32 + lh * 8);
  s16x8 b2fr[8][2];
#pragma unroll
  for (int ct2 = 0; ct2 < 8; ct2++)
#pragma unroll
    for (int kt = 0; kt < 2; kt++)
      b2fr[ct2][kt] = *reinterpret_cast<const s16x8*>(W2p + ((ct2 * 2 + kt) * 4 + lh) * 128 + ll * 8);
  float4 b1v[4];
#pragma unroll
  for (int ct = 0; ct < 4; ct++)
    b1v[ct] = *reinterpret_cast<const float4*>(b1 + ct * 16 + lh * 4);
  // K-extension fragments (bias): only (lh==0, j==0) slot nonzero
  s16x8 b2ext[8];
#pragma unroll
  for (int ct2 = 0; ct2 < 8; ct2++) {
    s16x8 v = (s16x8){0, 0, 0, 0, 0, 0, 0, 0};
    v[0] = (lh == 0) ? b2p[ct2 * 16 + ll] : (short)0;
    b2ext[ct2] = v;
  }
  s16x8 onef = (s16x8){0, 0, 0, 0, 0, 0, 0, 0};
  onef[0] = (lh == 0) ? (short)0x3F80 : (short)0;  // bf16(1.0)

  const f32x4 z = {0.f, 0.f, 0.f, 0.f};

#pragma unroll
  for (int mt = 0; mt < 4; mt++) {
    // A-operand of GEMM1' B-side: attr row for edge = mt*16 + ll
    int rowA = min(ebase + mt * 16 + ll, E - 1);
    const float4* ap = reinterpret_cast<const float4*>(attr + (size_t)rowA * EDIM + lh * 8);
    float4 a0 = ap[0], a1 = ap[1];
    s16x8 af;
    af[0]=f2b(a0.x); af[1]=f2b(a0.y); af[2]=f2b(a0.z); af[3]=f2b(a0.w);
    af[4]=f2b(a1.x); af[5]=f2b(a1.y); af[6]=f2b(a1.z); af[7]=f2b(a1.w);

    // GEMM1' -> H^T fragments
    f32x4 c1t[4];
#pragma unroll
    for (int ct = 0; ct < 4; ct++)
      c1t[ct] = __builtin_amdgcn_mfma_f32_16x16x32_bf16(b1f[ct], af, z, 0, 0, 0);

    short hb[4][4];
#pragma unroll
    for (int ct = 0; ct < 4; ct++) {
      hb[ct][0] = f2b(fmaxf(c1t[ct][0] + b1v[ct].x, 0.f));
      hb[ct][1] = f2b(fmaxf(c1t[ct][1] + b1v[ct].y, 0.f));
      hb[ct][2] = f2b(fmaxf(c1t[ct][2] + b1v[ct].z, 0.f));
      hb[ct][3] = f2b(fmaxf(c1t[ct][3] + b1v[ct].w, 0.f));
    }
    s16x8 a2f0, a2f1;
#pragma unroll
    for (int j = 0; j < 8; j++) a2f0[j] = hb[(j >> 2)][j & 3];
#pragma unroll
    for (int j = 0; j < 8; j++) a2f1[j] = hb[2 + (j >> 2)][j & 3];

    // fetch xe pairs of edge mt*16+ll (source lane's packed bf16)
    const int srcl = mt * 16 + ll;
    unsigned int xs[8];
#pragma unroll
    for (int c = 0; c < 8; c++)
      xs[c] = (unsigned int)__shfl((int)xqp[c], srcl, 64);

    // GEMM2' + K-ext bias + lane-local epilogue
    float q0 = 0.f, q1 = 0.f;
#pragma unroll
    for (int ct2 = 0; ct2 < 8; ct2++) {
      f32x4 c2 = __builtin_amdgcn_mfma_f32_16x16x32_bf16(b2fr[ct2][0], a2f0, z, 0, 0, 0);
      c2 = __builtin_amdgcn_mfma_f32_16x16x32_bf16(b2fr[ct2][1], a2f1, c2, 0, 0, 0);
      c2 = __builtin_amdgcn_mfma_f32_16x16x32_bf16(b2ext[ct2], onef, c2, 0, 0, 0);
      float xv0 = asf(xs[ct2] << 16);          // xe[2*ct2]
      float xv1 = asf(xs[ct2] & 0xffff0000u);  // xe[2*ct2+1]
      q0 = fmaf(xv0, c2[0], q0);
      q1 = fmaf(xv0, c2[1], q1);
      q0 = fmaf(xv1, c2[2], q0);
      q1 = fmaf(xv1, c2[3], q1);
    }
    int e = ebase + mt * 16 + ll;
    if (e < E)
      *reinterpret_cast<float2*>(ms + (size_t)e * LAT + 2 * lh) = make_float2(q0, q1);
  }
}

// ---------------------------------------------------------------------------
// Aggregate via eid gather + root weight -> latent
// ---------------------------------------------------------------------------
__global__ __launch_bounds__(256) void agg_latent_kernel(
    const float* __restrict__ emb, const float* __restrict__ ms,
    const int* __restrict__ offs, const int* __restrict__ deg,
    const int* __restrict__ eid,
    const float* __restrict__ rootW, const float* __restrict__ convb,
    float* __restrict__ latent, int N) {
  int n = blockIdx.x * blockDim.x + threadIdx.x;
  if (n >= N) return;
  int start = offs[n];
  int d = deg[n];

  float r[LAT];
#pragma unroll
  for (int o = 0; o < LAT; o++) r[o] = 0.f;

  const float4* mp = reinterpret_cast<const float4*>(ms);
  for (int j = 0; j < d; j++) {
    int e = eid[start + j];
    float4 a = mp[(size_t)e * 2];
    float4 b = mp[(size_t)e * 2 + 1];
    r[0] += a.x; r[1] += a.y; r[2] += a.z; r[3] += a.w;
    r[4] += b.x; r[5] += b.y; r[6] += b.z; r[7] += b.w;
  }

  float inv = 1.f / fmaxf((float)d, 1.f);
#pragma unroll
  for (int o = 0; o < LAT; o++) r[o] = fmaf(r[o], inv, convb[o]);

  float x[EMB];
  const float4* np4 = reinterpret_cast<const float4*>(emb) + (size_t)n * (EMB / 4);
#pragma unroll
  for (int i = 0; i < EMB / 4; i++) {
    float4 v = np4[i];
    x[4 * i + 0] = v.x; x[4 * i + 1] = v.y; x[4 * i + 2] = v.z; x[4 * i + 3] = v.w;
  }
#pragma unroll
  for (int i = 0; i < EMB; i++)
#pragma unroll
    for (int o = 0; o < LAT; o++) r[o] = fmaf(x[i], rootW[i * LAT + o], r[o]);

  float4* lp = reinterpret_cast<float4*>(latent) + (size_t)n * 2;
  lp[0] = make_float4(r[0], r[1], r[2], r[3]);
  lp[1] = make_float4(r[4], r[5], r[6], r[7]);
}

// ---------------------------------------------------------------------------
// Decoder: transposed GEMM2 -> coalesced float4 stores; zero LDS.
// ---------------------------------------------------------------------------
__global__ __launch_bounds__(256, 4) void dec_mfma_kernel(
    const int* __restrict__ ei, const float* __restrict__ lat,
    const short* __restrict__ dW1c, const float* __restrict__ db1,
    const short* __restrict__ dW2p, const float* __restrict__ db2,
    float* __restrict__ out, int E) {
  const int tid = threadIdx.x;
  const int w = tid >> 6, l = tid & 63;
  const int lh = l >> 4, ll = l & 15;
  const int ebase = blockIdx.x * 256 + w * 64;

  s16x8 b1f[4];
#pragma unroll
  for (int ct = 0; ct < 4; ct++) {
    if (lh < 2)
      b1f[ct] = *reinterpret_cast<const s16x8*>(dW1c + (ct * 16 + ll) * 16 + lh * 8);
    else
      b1f[ct] = (s16x8){0, 0, 0, 0, 0, 0, 0, 0};
  }
  s16x8 b2fr[2][2];
#pragma unroll
  for (int ct2 = 0; ct2 < 2; ct2++)
#pragma unroll
    for (int kt = 0; kt < 2; kt++)
      b2fr[ct2][kt] = *reinterpret_cast<const s16x8*>(dW2p + ((ct2 * 2 + kt) * 4 + lh) * 128 + ll * 8);
  float4 b1v[4];
#pragma unroll
  for (int ct = 0; ct < 4; ct++)
    b1v[ct] = *reinterpret_cast<const float4*>(db1 + ct * 16 + lh * 4);
  float4 b2v[2];
#pragma unroll
  for (int ct2 = 0; ct2 < 2; ct2++)
    b2v[ct2] = *reinterpret_cast<const float4*>(db2 + ct2 * 16 + lh * 4);

  // latent halves: lh=0 -> src, lh=1 -> tgt, lh>=2 zero pad (k 16..31)
  float4 pl[4][2];
#pragma unroll
  for (int mt = 0; mt < 4; mt++) {
    if (lh < 2) {
      int rowA = min(ebase + mt * 16 + ll, E - 1);
      int node = ei[(lh == 0 ? 0 : E) + rowA];
      const float4* lp = reinterpret_cast<const float4*>(lat + (size_t)node * LAT);
      pl[mt][0] = lp[0];
      pl[mt][1] = lp[1];
    } else {
      pl[mt][0] = make_float4(0.f, 0.f, 0.f, 0.f);
      pl[mt][1] = make_float4(0.f, 0.f, 0.f, 0.f);
    }
  }

  const f32x4 z = {0.f, 0.f, 0.f, 0.f};

#pragma unroll
  for (int mt = 0; mt < 4; mt++) {
    s16x8 af = (s16x8){0, 0, 0, 0, 0, 0, 0, 0};
    if (lh < 2) {
      af[0]=f2b(pl[mt][0].x); af[1]=f2b(pl[mt][0].y);
      af[2]=f2b(pl[mt][0].z); af[3]=f2b(pl[mt][0].w);
      af[4]=f2b(pl[mt][1].x); af[5]=f2b(pl[mt][1].y);
      af[6]=f2b(pl[mt][1].z); af[7]=f2b(pl[mt][1].w);
    }
    f32x4 c1t[4];
#pragma unroll
    for (int ct = 0; ct < 4; ct++)
      c1t[ct] = __builtin_amdgcn_mfma_f32_16x16x32_bf16(b1f[ct], af, z, 0, 0, 0);

    short hb[4][4];
#pragma unroll
    for (int ct = 0; ct < 4; ct++) {
      hb[ct][0] = f2b(fmaxf(c1t[ct][0] + b1v[ct].x, 0.f));
      hb[ct][1] = f2b(fmaxf(c1t[ct][1] + b1v[ct].y, 0.f));
      hb[ct][2] = f2b(fmaxf(c1t[ct][2] + b1v[ct].z, 0.f));
      hb[ct][3] = f2b(fmaxf(c1t[ct][3] + b1v[ct].w, 0.f));
    }
    s16x8 a2f0, a2f1;
#pragma unroll
    for (int j = 0; j < 8; j++) a2f0[j] = hb[(j >> 2)][j & 3];
#pragma unroll
    for (int j = 0; j < 8; j++) a2f1[j] = hb[2 + (j >> 2)][j & 3];

    int e = ebase + mt * 16 + ll;
#pragma unroll
    for (int ct2 = 0; ct2 < 2; ct2++) {
      f32x4 c2 = __builtin_amdgcn_mfma_f32_16x16x32_bf16(b2fr[ct2][0], a2f0, z, 0, 0, 0);
      c2 = __builtin_amdgcn_mfma_f32_16x16x32_bf16(b2fr[ct2][1], a2f1, c2, 0, 0, 0);
      if (e < E)
        *reinterpret_cast<float4*>(out + (size_t)e * EDIM + ct2 * 16 + lh * 4) =
            make_float4(c2[0] + b2v[ct2].x, c2[1] + b2v[ct2].y,
                        c2[2] + b2v[ct2].z, c2[3] + b2v[ct2].w);
    }
  }
}

// ---------------------------------------------------------------------------
extern "C" void kernel_launch(void* const* d_in, const int* in_sizes, int n_in,
                              void* d_out, int out_size, void* d_ws, size_t ws_size,
                              hipStream_t stream) {
  const int*   ei    = (const int*)  d_in[0];
  const float* attr  = (const float*)d_in[1];
  const float* emb   = (const float*)d_in[2];
  const float* ewW1  = (const float*)d_in[3];
  const float* ewb1  = (const float*)d_in[4];
  const float* ewW2  = (const float*)d_in[5];
  const float* ewb2  = (const float*)d_in[6];
  const float* rootW = (const float*)d_in[7];
  const float* convb = (const float*)d_in[8];
  const float* dW1   = (const float*)d_in[9];
  const float* db1   = (const float*)d_in[10];
  const float* dW2   = (const float*)d_in[11];
  const float* db2   = (const float*)d_in[12];
  float* out = (float*)d_out;

  const int E  = in_sizes[0] / 2;
  const int N  = in_sizes[2] / EMB;
  const int NB = (N + SCAN_TILE - 1) / SCAN_TILE;

  // workspace layout (weights first: 16B-aligned fragment loads)
  short* W1c  = (short*)d_ws;               // 2048
  short* W2p  = W1c + 64 * 32;              // 8192
  short* dW1c = W2p + 8192;                 // 1024
  short* dW2p = dW1c + 64 * 16;             // 2048
  short* b2p  = dW2p + 2048;                // 128  (13440 shorts = 26880 B)
  float* ms   = (float*)(b2p + 128);        // E*8
  float* lat  = ms + (size_t)E * LAT;       // N*8
  int*   deg    = (int*)(lat + (size_t)N * LAT);
  int*   loc    = deg + N;
  int*   offs   = loc + N;
  int*   cursor = offs + N;
  int*   eid    = cursor + N;               // E
  int*   bsum   = eid + E;                  // NB

  const int blocks_e = (E + 255) / 256;
  const int blocks_n = (N + 255) / 256;

  hipMemsetAsync(deg, 0, (size_t)N * sizeof(int), stream);
  prep_kernel<<<32, 256, 0, stream>>>(ewW1, ewW2, ewb2, dW1, dW2,
                                      W1c, W2p, b2p, dW1c, dW2p);
  enc_mfma_kernel<<<blocks_e, 256, 0, stream>>>(ei, attr, emb, W1c, ewb1, W2p, b2p,
                                                ms, E);
  hist_kernel<<<blocks_e, 256, 0, stream>>>(ei, deg, E);
  scan1_kernel<<<NB, SCAN_BLK, 0, stream>>>(deg, loc, bsum, N);
  scan2_kernel<<<1, SCAN_BLK, 0, stream>>>(bsum, NB);
  scan3_kernel<<<blocks_n, 256, 0, stream>>>(loc, bsum, offs, cursor, N);
  fill_kernel<<<blocks_e, 256, 0, stream>>>(ei, cursor, eid, E);
  agg_latent_kernel<<<blocks_n, 256, 0, stream>>>(emb, ms, offs, deg, eid,
                                                  rootW, convb, lat, N);
  dec_mfma_kernel<<<blocks_e, 256, 0, stream>>>(ei, lat, dW1c, db1, dW2p, db2, out, E);
}

// Round 6
// 429.786 us; speedup vs baseline: 1.8191x; 1.8191x over previous
//
#include <hip/hip_runtime.h>
#include <hip/hip_bf16.h>

typedef __attribute__((ext_vector_type(8))) short  s16x8;
typedef __attribute__((ext_vector_type(4))) float  f32x4;

constexpr int EMB  = 16;
constexpr int LAT  = 8;
constexpr int EDIM = 32;
constexpr int HID  = 64;

constexpr int SCAN_BLK   = 256;
constexpr int SCAN_ITEMS = 4;
constexpr int SCAN_TILE  = SCAN_BLK * SCAN_ITEMS;  // 1024

__device__ __forceinline__ short f2b(float f) {
  __hip_bfloat16 h = __float2bfloat16(f);
  return __builtin_bit_cast(short, h);
}
__device__ __forceinline__ float asf(unsigned int u) { return __builtin_bit_cast(float, u); }

// ---------------------------------------------------------------------------
// Prep (all bf16):
//  W1c  [64 hid][32 k]  = ew_W1^T                       (GEMM1' A-operand)
//  W2p  GEMM2' A-fragments with k-map g(kt,lh,j)=(kt*2+(j>>2))*16+lh*4+(j&3)
//       and column permutation pi: tile-row r, tile ct2 ->
//       i = 2*ct2 + ((r>>1)&1),  o = 2*(r>>2) + (r&1)   (i*8+o = W2 column)
//  b2pp [lh][ct2*2+ih] packed u32: lo=bf16(b2[i*8+2lh]), hi=bf16(b2[i*8+2lh+1])
//       with i = 2*ct2+ih   (per-lane epilogue bias constants)
//  dW1c [64 hid][16 k] = dec_W1^T
//  dW2p dec GEMM2' A-fragments, identity column map (col = ct2*16 + r)
// ---------------------------------------------------------------------------
__global__ void prep_kernel(const float* __restrict__ W1, const float* __restrict__ W2,
                            const float* __restrict__ b2,
                            const float* __restrict__ dW1, const float* __restrict__ dW2,
                            short* __restrict__ W1c, short* __restrict__ W2p,
                            unsigned int* __restrict__ b2pp,
                            short* __restrict__ dW1c, short* __restrict__ dW2p) {
  int t = blockIdx.x * blockDim.x + threadIdx.x;
  if (t < 64 * 32) { int c = t / 32, k = t % 32; W1c[t] = f2b(W1[k * 64 + c]); }
  if (t < 8192) {
    int ct2 = t >> 10, kt = (t >> 9) & 1, lh = (t >> 7) & 3, r = (t >> 3) & 15, j = t & 7;
    int k = (kt * 2 + (j >> 2)) * 16 + lh * 4 + (j & 3);
    int i = 2 * ct2 + ((r >> 1) & 1);
    int o = 2 * (r >> 2) + (r & 1);
    W2p[t] = f2b(W2[k * 128 + i * 8 + o]);
  }
  if (t < 64) {
    int lh = t >> 4, slot = t & 15;
    int ct2 = slot >> 1, ih = slot & 1;
    int i = 2 * ct2 + ih;
    unsigned int lo = (unsigned short)f2b(b2[i * 8 + 2 * lh]);
    unsigned int hi = (unsigned short)f2b(b2[i * 8 + 2 * lh + 1]);
    b2pp[t] = (hi << 16) | lo;
  }
  if (t < 64 * 16) { int c = t / 16, k = t % 16; dW1c[t] = f2b(dW1[k * 64 + c]); }
  if (t < 2048) {
    int ct2 = t >> 10, kt = (t >> 9) & 1, lh = (t >> 7) & 3, r = (t >> 3) & 15, j = t & 7;
    int k = (kt * 2 + (j >> 2)) * 16 + lh * 4 + (j & 3);
    dW2p[t] = f2b(dW2[k * 32 + ct2 * 16 + r]);
  }
}

// ---------------------------------------------------------------------------
// CSR build: histogram + exclusive scan + edge-id fill
// ---------------------------------------------------------------------------
__global__ __launch_bounds__(256) void hist_kernel(const int* __restrict__ ei,
                                                   int* __restrict__ deg, int E) {
  int e = blockIdx.x * blockDim.x + threadIdx.x;
  if (e < E) atomicAdd(&deg[ei[E + e]], 1);
}

__global__ __launch_bounds__(SCAN_BLK) void scan1_kernel(
    const int* __restrict__ deg, int* __restrict__ loc,
    int* __restrict__ bsum, int N) {
  __shared__ int sh[SCAN_BLK];
  int tid  = threadIdx.x;
  int base = blockIdx.x * SCAN_TILE + tid * SCAN_ITEMS;
  int v[SCAN_ITEMS];
  int s = 0;
#pragma unroll
  for (int j = 0; j < SCAN_ITEMS; j++) {
    v[j] = (base + j < N) ? deg[base + j] : 0;
    s += v[j];
  }
  sh[tid] = s;
  __syncthreads();
  for (int off = 1; off < SCAN_BLK; off <<= 1) {
    int t = (tid >= off) ? sh[tid - off] : 0;
    __syncthreads();
    sh[tid] += t;
    __syncthreads();
  }
  int p = sh[tid] - s;
#pragma unroll
  for (int j = 0; j < SCAN_ITEMS; j++) {
    if (base + j < N) loc[base + j] = p;
    p += v[j];
  }
  if (tid == SCAN_BLK - 1) bsum[blockIdx.x] = sh[tid];
}

__global__ __launch_bounds__(SCAN_BLK) void scan2_kernel(int* __restrict__ bsum, int NB) {
  __shared__ int sh[SCAN_BLK];
  int tid  = threadIdx.x;
  int base = tid * SCAN_ITEMS;
  int v[SCAN_ITEMS];
  int s = 0;
#pragma unroll
  for (int j = 0; j < SCAN_ITEMS; j++) {
    v[j] = (base + j < NB) ? bsum[base + j] : 0;
    s += v[j];
  }
  sh[tid] = s;
  __syncthreads();
  for (int off = 1; off < SCAN_BLK; off <<= 1) {
    int t = (tid >= off) ? sh[tid - off] : 0;
    __syncthreads();
    sh[tid] += t;
    __syncthreads();
  }
  int p = sh[tid] - s;
#pragma unroll
  for (int j = 0; j < SCAN_ITEMS; j++) {
    if (base + j < NB) bsum[base + j] = p;
    p += v[j];
  }
}

__global__ __launch_bounds__(256) void scan3_kernel(
    const int* __restrict__ loc, const int* __restrict__ bsum,
    int* __restrict__ offs, int* __restrict__ cursor, int N) {
  int i = blockIdx.x * blockDim.x + threadIdx.x;
  if (i < N) {
    int v = loc[i] + bsum[i / SCAN_TILE];
    offs[i] = v;
    cursor[i] = v;
  }
}

__global__ __launch_bounds__(256) void fill_kernel(const int* __restrict__ ei,
                                                   int* __restrict__ cursor,
                                                   int* __restrict__ eid, int E) {
  int e = blockIdx.x * blockDim.x + threadIdx.x;
  if (e < E) {
    int pos = atomicAdd(&cursor[ei[E + e]], 1);
    eid[pos] = e;
  }
}

// ---------------------------------------------------------------------------
// Encoder: zero LDS, zero atomics, zero barriers. Per wave: 64 edges, 4 tiles.
// GEMM1' (transposed): lane(ll,lh) -> H[edge=ll][hid=ct*16+lh*4+reg]
// GEMM2' (transposed, pi-permuted cols):
//   lane(ll,lh) c2[reg] = G[i=2ct2+(reg>>1)][o=2lh+(reg&1)] of edge=ll
// Epilogue: q_o = sum_i xe_i * (c2 + b2), xe via bf16-packed shfl,
// b2 via 16 packed VGPR constants; coalesced float2 store in EDGE order.
// ---------------------------------------------------------------------------
__global__ __launch_bounds__(256, 2) void enc_mfma_kernel(
    const int* __restrict__ ei, const float* __restrict__ attr,
    const float* __restrict__ emb,
    const short* __restrict__ W1c, const float* __restrict__ b1,
    const short* __restrict__ W2p, const unsigned int* __restrict__ b2pp,
    float* __restrict__ ms, int E) {
  const int tid = threadIdx.x;
  const int w = tid >> 6, l = tid & 63;
  const int lh = l >> 4, ll = l & 15;
  const int ebase = blockIdx.x * 256 + w * 64;

  // phase 0: gather src embedding for this lane's edge, pack to bf16 pairs
  unsigned int xqp[8];
  {
    int ec = min(ebase + l, E - 1);
    int src = ei[ec];
    const float4* er = reinterpret_cast<const float4*>(emb) + (size_t)src * 4;
    float4 v0 = er[0], v1 = er[1], v2 = er[2], v3 = er[3];
    float xf[16] = {v0.x, v0.y, v0.z, v0.w, v1.x, v1.y, v1.z, v1.w,
                    v2.x, v2.y, v2.z, v2.w, v3.x, v3.y, v3.z, v3.w};
#pragma unroll
    for (int c = 0; c < 8; c++)
      xqp[c] = ((unsigned int)(unsigned short)f2b(xf[2 * c + 1]) << 16) |
               (unsigned int)(unsigned short)f2b(xf[2 * c]);
  }

  // weights (VGPR resident)
  s16x8 b1f[4];
#pragma unroll
  for (int ct = 0; ct < 4; ct++)
    b1f[ct] = *reinterpret_cast<const s16x8*>(W1c + (ct * 16 + ll) * 32 + lh * 8);
  s16x8 b2fr[8][2];
#pragma unroll
  for (int ct2 = 0; ct2 < 8; ct2++)
#pragma unroll
    for (int kt = 0; kt < 2; kt++)
      b2fr[ct2][kt] = *reinterpret_cast<const s16x8*>(W2p + ((ct2 * 2 + kt) * 4 + lh) * 128 + ll * 8);
  float4 b1v[4];
#pragma unroll
  for (int ct = 0; ct < 4; ct++)
    b1v[ct] = *reinterpret_cast<const float4*>(b1 + ct * 16 + lh * 4);
  // epilogue bias constants (packed bf16 pairs, 16 VGPRs)
  unsigned int b2pk[16];
#pragma unroll
  for (int s = 0; s < 16; s++) b2pk[s] = b2pp[lh * 16 + s];

  const f32x4 z = {0.f, 0.f, 0.f, 0.f};

#pragma unroll
  for (int mt = 0; mt < 4; mt++) {
    // attr row for edge = mt*16 + ll (B-operand of GEMM1')
    int rowA = min(ebase + mt * 16 + ll, E - 1);
    const float4* ap = reinterpret_cast<const float4*>(attr + (size_t)rowA * EDIM + lh * 8);
    float4 a0 = ap[0], a1 = ap[1];
    s16x8 af;
    af[0]=f2b(a0.x); af[1]=f2b(a0.y); af[2]=f2b(a0.z); af[3]=f2b(a0.w);
    af[4]=f2b(a1.x); af[5]=f2b(a1.y); af[6]=f2b(a1.z); af[7]=f2b(a1.w);

    // GEMM1' -> H^T fragments
    f32x4 c1t[4];
#pragma unroll
    for (int ct = 0; ct < 4; ct++)
      c1t[ct] = __builtin_amdgcn_mfma_f32_16x16x32_bf16(b1f[ct], af, z, 0, 0, 0);

    short hb[4][4];
#pragma unroll
    for (int ct = 0; ct < 4; ct++) {
      hb[ct][0] = f2b(fmaxf(c1t[ct][0] + b1v[ct].x, 0.f));
      hb[ct][1] = f2b(fmaxf(c1t[ct][1] + b1v[ct].y, 0.f));
      hb[ct][2] = f2b(fmaxf(c1t[ct][2] + b1v[ct].z, 0.f));
      hb[ct][3] = f2b(fmaxf(c1t[ct][3] + b1v[ct].w, 0.f));
    }
    s16x8 a2f0, a2f1;
#pragma unroll
    for (int j = 0; j < 8; j++) a2f0[j] = hb[(j >> 2)][j & 3];
#pragma unroll
    for (int j = 0; j < 8; j++) a2f1[j] = hb[2 + (j >> 2)][j & 3];

    // fetch xe pairs of edge mt*16+ll (source lane's packed bf16)
    const int srcl = mt * 16 + ll;
    unsigned int xs[8];
#pragma unroll
    for (int c = 0; c < 8; c++)
      xs[c] = (unsigned int)__shfl((int)xqp[c], srcl, 64);

    // GEMM2' + lane-local epilogue with bias
    float q0 = 0.f, q1 = 0.f;
#pragma unroll
    for (int ct2 = 0; ct2 < 8; ct2++) {
      f32x4 c2 = __builtin_amdgcn_mfma_f32_16x16x32_bf16(b2fr[ct2][0], a2f0, z, 0, 0, 0);
      c2 = __builtin_amdgcn_mfma_f32_16x16x32_bf16(b2fr[ct2][1], a2f1, c2, 0, 0, 0);
      unsigned int p0 = b2pk[2 * ct2], p1 = b2pk[2 * ct2 + 1];
      float b00 = asf(p0 << 16), b01 = asf(p0 & 0xffff0000u);
      float b10 = asf(p1 << 16), b11 = asf(p1 & 0xffff0000u);
      float xv0 = asf(xs[ct2] << 16);          // xe[2*ct2]
      float xv1 = asf(xs[ct2] & 0xffff0000u);  // xe[2*ct2+1]
      q0 = fmaf(xv0, c2[0] + b00, q0);
      q1 = fmaf(xv0, c2[1] + b01, q1);
      q0 = fmaf(xv1, c2[2] + b10, q0);
      q1 = fmaf(xv1, c2[3] + b11, q1);
    }
    int e = ebase + mt * 16 + ll;
    if (e < E)
      *reinterpret_cast<float2*>(ms + (size_t)e * LAT + 2 * lh) = make_float2(q0, q1);
  }
}

// ---------------------------------------------------------------------------
// Aggregate via eid gather + root weight -> latent
// ---------------------------------------------------------------------------
__global__ __launch_bounds__(256) void agg_latent_kernel(
    const float* __restrict__ emb, const float* __restrict__ ms,
    const int* __restrict__ offs, const int* __restrict__ deg,
    const int* __restrict__ eid,
    const float* __restrict__ rootW, const float* __restrict__ convb,
    float* __restrict__ latent, int N) {
  int n = blockIdx.x * blockDim.x + threadIdx.x;
  if (n >= N) return;
  int start = offs[n];
  int d = deg[n];

  float r[LAT];
#pragma unroll
  for (int o = 0; o < LAT; o++) r[o] = 0.f;

  const float4* mp = reinterpret_cast<const float4*>(ms);
  for (int j = 0; j < d; j++) {
    int e = eid[start + j];
    float4 a = mp[(size_t)e * 2];
    float4 b = mp[(size_t)e * 2 + 1];
    r[0] += a.x; r[1] += a.y; r[2] += a.z; r[3] += a.w;
    r[4] += b.x; r[5] += b.y; r[6] += b.z; r[7] += b.w;
  }

  float inv = 1.f / fmaxf((float)d, 1.f);
#pragma unroll
  for (int o = 0; o < LAT; o++) r[o] = fmaf(r[o], inv, convb[o]);

  float x[EMB];
  const float4* np4 = reinterpret_cast<const float4*>(emb) + (size_t)n * (EMB / 4);
#pragma unroll
  for (int i = 0; i < EMB / 4; i++) {
    float4 v = np4[i];
    x[4 * i + 0] = v.x; x[4 * i + 1] = v.y; x[4 * i + 2] = v.z; x[4 * i + 3] = v.w;
  }
#pragma unroll
  for (int i = 0; i < EMB; i++)
#pragma unroll
    for (int o = 0; o < LAT; o++) r[o] = fmaf(x[i], rootW[i * LAT + o], r[o]);

  float4* lp = reinterpret_cast<float4*>(latent) + (size_t)n * 2;
  lp[0] = make_float4(r[0], r[1], r[2], r[3]);
  lp[1] = make_float4(r[4], r[5], r[6], r[7]);
}

// ---------------------------------------------------------------------------
// Decoder: transposed GEMM2 -> coalesced float4 stores; zero LDS.
// ---------------------------------------------------------------------------
__global__ __launch_bounds__(256, 2) void dec_mfma_kernel(
    const int* __restrict__ ei, const float* __restrict__ lat,
    const short* __restrict__ dW1c, const float* __restrict__ db1,
    const short* __restrict__ dW2p, const float* __restrict__ db2,
    float* __restrict__ out, int E) {
  const int tid = threadIdx.x;
  const int w = tid >> 6, l = tid & 63;
  const int lh = l >> 4, ll = l & 15;
  const int ebase = blockIdx.x * 256 + w * 64;

  s16x8 b1f[4];
#pragma unroll
  for (int ct = 0; ct < 4; ct++) {
    if (lh < 2)
      b1f[ct] = *reinterpret_cast<const s16x8*>(dW1c + (ct * 16 + ll) * 16 + lh * 8);
    else
      b1f[ct] = (s16x8){0, 0, 0, 0, 0, 0, 0, 0};
  }
  s16x8 b2fr[2][2];
#pragma unroll
  for (int ct2 = 0; ct2 < 2; ct2++)
#pragma unroll
    for (int kt = 0; kt < 2; kt++)
      b2fr[ct2][kt] = *reinterpret_cast<const s16x8*>(dW2p + ((ct2 * 2 + kt) * 4 + lh) * 128 + ll * 8);
  float4 b1v[4];
#pragma unroll
  for (int ct = 0; ct < 4; ct++)
    b1v[ct] = *reinterpret_cast<const float4*>(db1 + ct * 16 + lh * 4);
  float4 b2v[2];
#pragma unroll
  for (int ct2 = 0; ct2 < 2; ct2++)
    b2v[ct2] = *reinterpret_cast<const float4*>(db2 + ct2 * 16 + lh * 4);

  // latent halves: lh=0 -> src, lh=1 -> tgt, lh>=2 zero pad (k 16..31)
  float4 pl[4][2];
#pragma unroll
  for (int mt = 0; mt < 4; mt++) {
    if (lh < 2) {
      int rowA = min(ebase + mt * 16 + ll, E - 1);
      int node = ei[(lh == 0 ? 0 : E) + rowA];
      const float4* lp = reinterpret_cast<const float4*>(lat + (size_t)node * LAT);
      pl[mt][0] = lp[0];
      pl[mt][1] = lp[1];
    } else {
      pl[mt][0] = make_float4(0.f, 0.f, 0.f, 0.f);
      pl[mt][1] = make_float4(0.f, 0.f, 0.f, 0.f);
    }
  }

  const f32x4 z = {0.f, 0.f, 0.f, 0.f};

#pragma unroll
  for (int mt = 0; mt < 4; mt++) {
    s16x8 af = (s16x8){0, 0, 0, 0, 0, 0, 0, 0};
    if (lh < 2) {
      af[0]=f2b(pl[mt][0].x); af[1]=f2b(pl[mt][0].y);
      af[2]=f2b(pl[mt][0].z); af[3]=f2b(pl[mt][0].w);
      af[4]=f2b(pl[mt][1].x); af[5]=f2b(pl[mt][1].y);
      af[6]=f2b(pl[mt][1].z); af[7]=f2b(pl[mt][1].w);
    }
    f32x4 c1t[4];
#pragma unroll
    for (int ct = 0; ct < 4; ct++)
      c1t[ct] = __builtin_amdgcn_mfma_f32_16x16x32_bf16(b1f[ct], af, z, 0, 0, 0);

    short hb[4][4];
#pragma unroll
    for (int ct = 0; ct < 4; ct++) {
      hb[ct][0] = f2b(fmaxf(c1t[ct][0] + b1v[ct].x, 0.f));
      hb[ct][1] = f2b(fmaxf(c1t[ct][1] + b1v[ct].y, 0.f));
      hb[ct][2] = f2b(fmaxf(c1t[ct][2] + b1v[ct].z, 0.f));
      hb[ct][3] = f2b(fmaxf(c1t[ct][3] + b1v[ct].w, 0.f));
    }
    s16x8 a2f0, a2f1;
#pragma unroll
    for (int j = 0; j < 8; j++) a2f0[j] = hb[(j >> 2)][j & 3];
#pragma unroll
    for (int j = 0; j < 8; j++) a2f1[j] = hb[2 + (j >> 2)][j & 3];

    int e = ebase + mt * 16 + ll;
#pragma unroll
    for (int ct2 = 0; ct2 < 2; ct2++) {
      f32x4 c2 = __builtin_amdgcn_mfma_f32_16x16x32_bf16(b2fr[ct2][0], a2f0, z, 0, 0, 0);
      c2 = __builtin_amdgcn_mfma_f32_16x16x32_bf16(b2fr[ct2][1], a2f1, c2, 0, 0, 0);
      if (e < E)
        *reinterpret_cast<float4*>(out + (size_t)e * EDIM + ct2 * 16 + lh * 4) =
            make_float4(c2[0] + b2v[ct2].x, c2[1] + b2v[ct2].y,
                        c2[2] + b2v[ct2].z, c2[3] + b2v[ct2].w);
    }
  }
}

// ---------------------------------------------------------------------------
extern "C" void kernel_launch(void* const* d_in, const int* in_sizes, int n_in,
                              void* d_out, int out_size, void* d_ws, size_t ws_size,
                              hipStream_t stream) {
  const int*   ei    = (const int*)  d_in[0];
  const float* attr  = (const float*)d_in[1];
  const float* emb   = (const float*)d_in[2];
  const float* ewW1  = (const float*)d_in[3];
  const float* ewb1  = (const float*)d_in[4];
  const float* ewW2  = (const float*)d_in[5];
  const float* ewb2  = (const float*)d_in[6];
  const float* rootW = (const float*)d_in[7];
  const float* convb = (const float*)d_in[8];
  const float* dW1   = (const float*)d_in[9];
  const float* db1   = (const float*)d_in[10];
  const float* dW2   = (const float*)d_in[11];
  const float* db2   = (const float*)d_in[12];
  float* out = (float*)d_out;

  const int E  = in_sizes[0] / 2;
  const int N  = in_sizes[2] / EMB;
  const int NB = (N + SCAN_TILE - 1) / SCAN_TILE;

  // workspace layout (weights first: 16B-aligned fragment loads)
  short* W1c  = (short*)d_ws;                   // 2048
  short* W2p  = W1c + 64 * 32;                  // 8192
  short* dW1c = W2p + 8192;                     // 1024
  short* dW2p = dW1c + 64 * 16;                 // 2048
  unsigned int* b2pp = (unsigned int*)(dW2p + 2048);  // 64 u32
  float* ms   = (float*)(b2pp + 64);            // E*8
  float* lat  = ms + (size_t)E * LAT;           // N*8
  int*   deg    = (int*)(lat + (size_t)N * LAT);
  int*   loc    = deg + N;
  int*   offs   = loc + N;
  int*   cursor = offs + N;
  int*   eid    = cursor + N;                   // E
  int*   bsum   = eid + E;                      // NB

  const int blocks_e = (E + 255) / 256;
  const int blocks_n = (N + 255) / 256;

  hipMemsetAsync(deg, 0, (size_t)N * sizeof(int), stream);
  prep_kernel<<<32, 256, 0, stream>>>(ewW1, ewW2, ewb2, dW1, dW2,
                                      W1c, W2p, b2pp, dW1c, dW2p);
  enc_mfma_kernel<<<blocks_e, 256, 0, stream>>>(ei, attr, emb, W1c, ewb1, W2p, b2pp,
                                                ms, E);
  hist_kernel<<<blocks_e, 256, 0, stream>>>(ei, deg, E);
  scan1_kernel<<<NB, SCAN_BLK, 0, stream>>>(deg, loc, bsum, N);
  scan2_kernel<<<1, SCAN_BLK, 0, stream>>>(bsum, NB);
  scan3_kernel<<<blocks_n, 256, 0, stream>>>(loc, bsum, offs, cursor, N);
  fill_kernel<<<blocks_e, 256, 0, stream>>>(ei, cursor, eid, E);
  agg_latent_kernel<<<blocks_n, 256, 0, stream>>>(emb, ms, offs, deg, eid,
                                                  rootW, convb, lat, N);
  dec_mfma_kernel<<<blocks_e, 256, 0, stream>>>(ei, lat, dW1c, db1, dW2p, db2, out, E);
}

// Round 7
// 329.947 us; speedup vs baseline: 2.3696x; 1.3026x over previous
//
#include <hip/hip_runtime.h>
#include <hip/hip_bf16.h>

typedef __attribute__((ext_vector_type(8))) short  s16x8;
typedef __attribute__((ext_vector_type(4))) float  f32x4;

constexpr int EMB  = 16;
constexpr int LAT  = 8;
constexpr int EDIM = 32;
constexpr int HID  = 64;

constexpr int SCAN_BLK   = 256;
constexpr int SCAN_ITEMS = 4;
constexpr int SCAN_TILE  = SCAN_BLK * SCAN_ITEMS;  // 1024

__device__ __forceinline__ short f2b(float f) {
  __hip_bfloat16 h = __float2bfloat16(f);
  return __builtin_bit_cast(short, h);
}
__device__ __forceinline__ float asf(unsigned int u) { return __builtin_bit_cast(float, u); }

// ---------------------------------------------------------------------------
// Prep (all bf16):
//  W1c  [64 hid][32 k]  = ew_W1^T                       (GEMM1' A-operand)
//  W2p  GEMM2' A-fragments with k-map g(kt,lh,j)=(kt*2+(j>>2))*16+lh*4+(j&3)
//       and column permutation pi: tile-row r, tile ct2 ->
//       i = 2*ct2 + ((r>>1)&1),  o = 2*(r>>2) + (r&1)   (i*8+o = W2 column)
//  b2pp [lh][ct2*2+ih] packed u32: lo=bf16(b2[i*8+2lh]), hi=bf16(b2[i*8+2lh+1])
//       with i = 2*ct2+ih   (per-lane epilogue bias constants)
//  dW1c [64 hid][16 k] = dec_W1^T
//  dW2p dec GEMM2' A-fragments, identity column map (col = ct2*16 + r)
// ---------------------------------------------------------------------------
__global__ void prep_kernel(const float* __restrict__ W1, const float* __restrict__ W2,
                            const float* __restrict__ b2,
                            const float* __restrict__ dW1, const float* __restrict__ dW2,
                            short* __restrict__ W1c, short* __restrict__ W2p,
                            unsigned int* __restrict__ b2pp,
                            short* __restrict__ dW1c, short* __restrict__ dW2p) {
  int t = blockIdx.x * blockDim.x + threadIdx.x;
  if (t < 64 * 32) { int c = t / 32, k = t % 32; W1c[t] = f2b(W1[k * 64 + c]); }
  if (t < 8192) {
    int ct2 = t >> 10, kt = (t >> 9) & 1, lh = (t >> 7) & 3, r = (t >> 3) & 15, j = t & 7;
    int k = (kt * 2 + (j >> 2)) * 16 + lh * 4 + (j & 3);
    int i = 2 * ct2 + ((r >> 1) & 1);
    int o = 2 * (r >> 2) + (r & 1);
    W2p[t] = f2b(W2[k * 128 + i * 8 + o]);
  }
  if (t < 64) {
    int lh = t >> 4, slot = t & 15;
    int ct2 = slot >> 1, ih = slot & 1;
    int i = 2 * ct2 + ih;
    unsigned int lo = (unsigned short)f2b(b2[i * 8 + 2 * lh]);
    unsigned int hi = (unsigned short)f2b(b2[i * 8 + 2 * lh + 1]);
    b2pp[t] = (hi << 16) | lo;
  }
  if (t < 64 * 16) { int c = t / 16, k = t % 16; dW1c[t] = f2b(dW1[k * 64 + c]); }
  if (t < 2048) {
    int ct2 = t >> 10, kt = (t >> 9) & 1, lh = (t >> 7) & 3, r = (t >> 3) & 15, j = t & 7;
    int k = (kt * 2 + (j >> 2)) * 16 + lh * 4 + (j & 3);
    dW2p[t] = f2b(dW2[k * 32 + ct2 * 16 + r]);
  }
}

// ---------------------------------------------------------------------------
// CSR build: histogram + exclusive scan
// ---------------------------------------------------------------------------
__global__ __launch_bounds__(256) void hist_kernel(const int* __restrict__ ei,
                                                   int* __restrict__ deg, int E) {
  int e = blockIdx.x * blockDim.x + threadIdx.x;
  if (e < E) atomicAdd(&deg[ei[E + e]], 1);
}

__global__ __launch_bounds__(SCAN_BLK) void scan1_kernel(
    const int* __restrict__ deg, int* __restrict__ loc,
    int* __restrict__ bsum, int N) {
  __shared__ int sh[SCAN_BLK];
  int tid  = threadIdx.x;
  int base = blockIdx.x * SCAN_TILE + tid * SCAN_ITEMS;
  int v[SCAN_ITEMS];
  int s = 0;
#pragma unroll
  for (int j = 0; j < SCAN_ITEMS; j++) {
    v[j] = (base + j < N) ? deg[base + j] : 0;
    s += v[j];
  }
  sh[tid] = s;
  __syncthreads();
  for (int off = 1; off < SCAN_BLK; off <<= 1) {
    int t = (tid >= off) ? sh[tid - off] : 0;
    __syncthreads();
    sh[tid] += t;
    __syncthreads();
  }
  int p = sh[tid] - s;
#pragma unroll
  for (int j = 0; j < SCAN_ITEMS; j++) {
    if (base + j < N) loc[base + j] = p;
    p += v[j];
  }
  if (tid == SCAN_BLK - 1) bsum[blockIdx.x] = sh[tid];
}

__global__ __launch_bounds__(SCAN_BLK) void scan2_kernel(int* __restrict__ bsum, int NB) {
  __shared__ int sh[SCAN_BLK];
  int tid  = threadIdx.x;
  int base = tid * SCAN_ITEMS;
  int v[SCAN_ITEMS];
  int s = 0;
#pragma unroll
  for (int j = 0; j < SCAN_ITEMS; j++) {
    v[j] = (base + j < NB) ? bsum[base + j] : 0;
    s += v[j];
  }
  sh[tid] = s;
  __syncthreads();
  for (int off = 1; off < SCAN_BLK; off <<= 1) {
    int t = (tid >= off) ? sh[tid - off] : 0;
    __syncthreads();
    sh[tid] += t;
    __syncthreads();
  }
  int p = sh[tid] - s;
#pragma unroll
  for (int j = 0; j < SCAN_ITEMS; j++) {
    if (base + j < NB) bsum[base + j] = p;
    p += v[j];
  }
}

__global__ __launch_bounds__(256) void scan3_kernel(
    const int* __restrict__ loc, const int* __restrict__ bsum,
    int* __restrict__ offs, int* __restrict__ cursor, int N) {
  int i = blockIdx.x * blockDim.x + threadIdx.x;
  if (i < N) {
    int v = loc[i] + bsum[i / SCAN_TILE];
    offs[i] = v;
    cursor[i] = v;
  }
}

// ---------------------------------------------------------------------------
// Encoder: zero LDS, zero barriers. Per wave: 64 edges, 4 tiles.
// Phase 0 claims the CSR slot (one int atomic/edge, latency hidden under the
// whole MFMA chain) and gathers the src embedding.
// GEMM1' (transposed): lane(ll,lh) -> H[edge=ll][hid=ct*16+lh*4+reg]
// GEMM2' (transposed, pi-permuted cols):
//   lane(ll,lh) c2[reg] = G[i=2ct2+(reg>>1)][o=2lh+(reg&1)] of edge=ll
// Epilogue: q_o = sum_i xe_i * (c2 + b2) lane-local; float2 store at the
// claimed CSR slot (the single scatter in the pipeline).
// ---------------------------------------------------------------------------
__global__ __launch_bounds__(256, 2) void enc_mfma_kernel(
    const int* __restrict__ ei, const float* __restrict__ attr,
    const float* __restrict__ emb,
    const short* __restrict__ W1c, const float* __restrict__ b1,
    const short* __restrict__ W2p, const unsigned int* __restrict__ b2pp,
    int* __restrict__ cursor, float* __restrict__ ms, int E) {
  const int tid = threadIdx.x;
  const int w = tid >> 6, l = tid & 63;
  const int lh = l >> 4, ll = l & 15;
  const int ebase = blockIdx.x * 256 + w * 64;

  // phase 0: claim CSR slot + gather src embedding, pack to bf16 pairs
  unsigned int xqp[8];
  int mypos = 0;
  {
    int e  = ebase + l;
    int ec = min(e, E - 1);
    int src = ei[ec];
    int tgt = ei[E + ec];
    if (e < E) mypos = atomicAdd(&cursor[tgt], 1);
    const float4* er = reinterpret_cast<const float4*>(emb) + (size_t)src * 4;
    float4 v0 = er[0], v1 = er[1], v2 = er[2], v3 = er[3];
    float xf[16] = {v0.x, v0.y, v0.z, v0.w, v1.x, v1.y, v1.z, v1.w,
                    v2.x, v2.y, v2.z, v2.w, v3.x, v3.y, v3.z, v3.w};
#pragma unroll
    for (int c = 0; c < 8; c++)
      xqp[c] = ((unsigned int)(unsigned short)f2b(xf[2 * c + 1]) << 16) |
               (unsigned int)(unsigned short)f2b(xf[2 * c]);
  }

  // weights (VGPR resident)
  s16x8 b1f[4];
#pragma unroll
  for (int ct = 0; ct < 4; ct++)
    b1f[ct] = *reinterpret_cast<const s16x8*>(W1c + (ct * 16 + ll) * 32 + lh * 8);
  s16x8 b2fr[8][2];
#pragma unroll
  for (int ct2 = 0; ct2 < 8; ct2++)
#pragma unroll
    for (int kt = 0; kt < 2; kt++)
      b2fr[ct2][kt] = *reinterpret_cast<const s16x8*>(W2p + ((ct2 * 2 + kt) * 4 + lh) * 128 + ll * 8);
  float4 b1v[4];
#pragma unroll
  for (int ct = 0; ct < 4; ct++)
    b1v[ct] = *reinterpret_cast<const float4*>(b1 + ct * 16 + lh * 4);
  // epilogue bias constants (packed bf16 pairs, 16 VGPRs)
  unsigned int b2pk[16];
#pragma unroll
  for (int s = 0; s < 16; s++) b2pk[s] = b2pp[lh * 16 + s];

  const f32x4 z = {0.f, 0.f, 0.f, 0.f};

#pragma unroll
  for (int mt = 0; mt < 4; mt++) {
    // attr row for edge = mt*16 + ll (B-operand of GEMM1')
    int rowA = min(ebase + mt * 16 + ll, E - 1);
    const float4* ap = reinterpret_cast<const float4*>(attr + (size_t)rowA * EDIM + lh * 8);
    float4 a0 = ap[0], a1 = ap[1];
    s16x8 af;
    af[0]=f2b(a0.x); af[1]=f2b(a0.y); af[2]=f2b(a0.z); af[3]=f2b(a0.w);
    af[4]=f2b(a1.x); af[5]=f2b(a1.y); af[6]=f2b(a1.z); af[7]=f2b(a1.w);

    // GEMM1' -> H^T fragments
    f32x4 c1t[4];
#pragma unroll
    for (int ct = 0; ct < 4; ct++)
      c1t[ct] = __builtin_amdgcn_mfma_f32_16x16x32_bf16(b1f[ct], af, z, 0, 0, 0);

    short hb[4][4];
#pragma unroll
    for (int ct = 0; ct < 4; ct++) {
      hb[ct][0] = f2b(fmaxf(c1t[ct][0] + b1v[ct].x, 0.f));
      hb[ct][1] = f2b(fmaxf(c1t[ct][1] + b1v[ct].y, 0.f));
      hb[ct][2] = f2b(fmaxf(c1t[ct][2] + b1v[ct].z, 0.f));
      hb[ct][3] = f2b(fmaxf(c1t[ct][3] + b1v[ct].w, 0.f));
    }
    s16x8 a2f0, a2f1;
#pragma unroll
    for (int j = 0; j < 8; j++) a2f0[j] = hb[(j >> 2)][j & 3];
#pragma unroll
    for (int j = 0; j < 8; j++) a2f1[j] = hb[2 + (j >> 2)][j & 3];

    // fetch xe pairs + CSR slot of edge mt*16+ll (from the owning lane)
    const int srcl = mt * 16 + ll;
    unsigned int xs[8];
#pragma unroll
    for (int c = 0; c < 8; c++)
      xs[c] = (unsigned int)__shfl((int)xqp[c], srcl, 64);
    int posv = __shfl(mypos, srcl, 64);

    // GEMM2' + lane-local epilogue with bias
    float q0 = 0.f, q1 = 0.f;
#pragma unroll
    for (int ct2 = 0; ct2 < 8; ct2++) {
      f32x4 c2 = __builtin_amdgcn_mfma_f32_16x16x32_bf16(b2fr[ct2][0], a2f0, z, 0, 0, 0);
      c2 = __builtin_amdgcn_mfma_f32_16x16x32_bf16(b2fr[ct2][1], a2f1, c2, 0, 0, 0);
      unsigned int p0 = b2pk[2 * ct2], p1 = b2pk[2 * ct2 + 1];
      float b00 = asf(p0 << 16), b01 = asf(p0 & 0xffff0000u);
      float b10 = asf(p1 << 16), b11 = asf(p1 & 0xffff0000u);
      float xv0 = asf(xs[ct2] << 16);          // xe[2*ct2]
      float xv1 = asf(xs[ct2] & 0xffff0000u);  // xe[2*ct2+1]
      q0 = fmaf(xv0, c2[0] + b00, q0);
      q1 = fmaf(xv0, c2[1] + b01, q1);
      q0 = fmaf(xv1, c2[2] + b10, q0);
      q1 = fmaf(xv1, c2[3] + b11, q1);
    }
    int e = ebase + mt * 16 + ll;
    if (e < E)
      *reinterpret_cast<float2*>(ms + (size_t)posv * LAT + 2 * lh) = make_float2(q0, q1);
  }
}

// ---------------------------------------------------------------------------
// Aggregate contiguous CSR message rows + root weight -> latent
// ---------------------------------------------------------------------------
__global__ __launch_bounds__(256) void agg_latent_kernel(
    const float* __restrict__ emb, const float* __restrict__ ms,
    const int* __restrict__ offs, const int* __restrict__ deg,
    const float* __restrict__ rootW, const float* __restrict__ convb,
    float* __restrict__ latent, int N) {
  int n = blockIdx.x * blockDim.x + threadIdx.x;
  if (n >= N) return;
  int start = offs[n];
  int d = deg[n];

  float r[LAT];
#pragma unroll
  for (int o = 0; o < LAT; o++) r[o] = 0.f;

  const float4* mp = reinterpret_cast<const float4*>(ms);
  for (int j = 0; j < d; j++) {
    float4 a = mp[(size_t)(start + j) * 2];
    float4 b = mp[(size_t)(start + j) * 2 + 1];
    r[0] += a.x; r[1] += a.y; r[2] += a.z; r[3] += a.w;
    r[4] += b.x; r[5] += b.y; r[6] += b.z; r[7] += b.w;
  }

  float inv = 1.f / fmaxf((float)d, 1.f);
#pragma unroll
  for (int o = 0; o < LAT; o++) r[o] = fmaf(r[o], inv, convb[o]);

  float x[EMB];
  const float4* np4 = reinterpret_cast<const float4*>(emb) + (size_t)n * (EMB / 4);
#pragma unroll
  for (int i = 0; i < EMB / 4; i++) {
    float4 v = np4[i];
    x[4 * i + 0] = v.x; x[4 * i + 1] = v.y; x[4 * i + 2] = v.z; x[4 * i + 3] = v.w;
  }
#pragma unroll
  for (int i = 0; i < EMB; i++)
#pragma unroll
    for (int o = 0; o < LAT; o++) r[o] = fmaf(x[i], rootW[i * LAT + o], r[o]);

  float4* lp = reinterpret_cast<float4*>(latent) + (size_t)n * 2;
  lp[0] = make_float4(r[0], r[1], r[2], r[3]);
  lp[1] = make_float4(r[4], r[5], r[6], r[7]);
}

// ---------------------------------------------------------------------------
// Decoder: transposed GEMM2 -> coalesced float4 stores; zero LDS.
// ---------------------------------------------------------------------------
__global__ __launch_bounds__(256, 2) void dec_mfma_kernel(
    const int* __restrict__ ei, const float* __restrict__ lat,
    const short* __restrict__ dW1c, const float* __restrict__ db1,
    const short* __restrict__ dW2p, const float* __restrict__ db2,
    float* __restrict__ out, int E) {
  const int tid = threadIdx.x;
  const int w = tid >> 6, l = tid & 63;
  const int lh = l >> 4, ll = l & 15;
  const int ebase = blockIdx.x * 256 + w * 64;

  s16x8 b1f[4];
#pragma unroll
  for (int ct = 0; ct < 4; ct++) {
    if (lh < 2)
      b1f[ct] = *reinterpret_cast<const s16x8*>(dW1c + (ct * 16 + ll) * 16 + lh * 8);
    else
      b1f[ct] = (s16x8){0, 0, 0, 0, 0, 0, 0, 0};
  }
  s16x8 b2fr[2][2];
#pragma unroll
  for (int ct2 = 0; ct2 < 2; ct2++)
#pragma unroll
    for (int kt = 0; kt < 2; kt++)
      b2fr[ct2][kt] = *reinterpret_cast<const s16x8*>(dW2p + ((ct2 * 2 + kt) * 4 + lh) * 128 + ll * 8);
  float4 b1v[4];
#pragma unroll
  for (int ct = 0; ct < 4; ct++)
    b1v[ct] = *reinterpret_cast<const float4*>(db1 + ct * 16 + lh * 4);
  float4 b2v[2];
#pragma unroll
  for (int ct2 = 0; ct2 < 2; ct2++)
    b2v[ct2] = *reinterpret_cast<const float4*>(db2 + ct2 * 16 + lh * 4);

  // latent halves: lh=0 -> src, lh=1 -> tgt, lh>=2 zero pad (k 16..31)
  float4 pl[4][2];
#pragma unroll
  for (int mt = 0; mt < 4; mt++) {
    if (lh < 2) {
      int rowA = min(ebase + mt * 16 + ll, E - 1);
      int node = ei[(lh == 0 ? 0 : E) + rowA];
      const float4* lp = reinterpret_cast<const float4*>(lat + (size_t)node * LAT);
      pl[mt][0] = lp[0];
      pl[mt][1] = lp[1];
    } else {
      pl[mt][0] = make_float4(0.f, 0.f, 0.f, 0.f);
      pl[mt][1] = make_float4(0.f, 0.f, 0.f, 0.f);
    }
  }

  const f32x4 z = {0.f, 0.f, 0.f, 0.f};

#pragma unroll
  for (int mt = 0; mt < 4; mt++) {
    s16x8 af = (s16x8){0, 0, 0, 0, 0, 0, 0, 0};
    if (lh < 2) {
      af[0]=f2b(pl[mt][0].x); af[1]=f2b(pl[mt][0].y);
      af[2]=f2b(pl[mt][0].z); af[3]=f2b(pl[mt][0].w);
      af[4]=f2b(pl[mt][1].x); af[5]=f2b(pl[mt][1].y);
      af[6]=f2b(pl[mt][1].z); af[7]=f2b(pl[mt][1].w);
    }
    f32x4 c1t[4];
#pragma unroll
    for (int ct = 0; ct < 4; ct++)
      c1t[ct] = __builtin_amdgcn_mfma_f32_16x16x32_bf16(b1f[ct], af, z, 0, 0, 0);

    short hb[4][4];
#pragma unroll
    for (int ct = 0; ct < 4; ct++) {
      hb[ct][0] = f2b(fmaxf(c1t[ct][0] + b1v[ct].x, 0.f));
      hb[ct][1] = f2b(fmaxf(c1t[ct][1] + b1v[ct].y, 0.f));
      hb[ct][2] = f2b(fmaxf(c1t[ct][2] + b1v[ct].z, 0.f));
      hb[ct][3] = f2b(fmaxf(c1t[ct][3] + b1v[ct].w, 0.f));
    }
    s16x8 a2f0, a2f1;
#pragma unroll
    for (int j = 0; j < 8; j++) a2f0[j] = hb[(j >> 2)][j & 3];
#pragma unroll
    for (int j = 0; j < 8; j++) a2f1[j] = hb[2 + (j >> 2)][j & 3];

    int e = ebase + mt * 16 + ll;
#pragma unroll
    for (int ct2 = 0; ct2 < 2; ct2++) {
      f32x4 c2 = __builtin_amdgcn_mfma_f32_16x16x32_bf16(b2fr[ct2][0], a2f0, z, 0, 0, 0);
      c2 = __builtin_amdgcn_mfma_f32_16x16x32_bf16(b2fr[ct2][1], a2f1, c2, 0, 0, 0);
      if (e < E)
        *reinterpret_cast<float4*>(out + (size_t)e * EDIM + ct2 * 16 + lh * 4) =
            make_float4(c2[0] + b2v[ct2].x, c2[1] + b2v[ct2].y,
                        c2[2] + b2v[ct2].z, c2[3] + b2v[ct2].w);
    }
  }
}

// ---------------------------------------------------------------------------
extern "C" void kernel_launch(void* const* d_in, const int* in_sizes, int n_in,
                              void* d_out, int out_size, void* d_ws, size_t ws_size,
                              hipStream_t stream) {
  const int*   ei    = (const int*)  d_in[0];
  const float* attr  = (const float*)d_in[1];
  const float* emb   = (const float*)d_in[2];
  const float* ewW1  = (const float*)d_in[3];
  const float* ewb1  = (const float*)d_in[4];
  const float* ewW2  = (const float*)d_in[5];
  const float* ewb2  = (const float*)d_in[6];
  const float* rootW = (const float*)d_in[7];
  const float* convb = (const float*)d_in[8];
  const float* dW1   = (const float*)d_in[9];
  const float* db1   = (const float*)d_in[10];
  const float* dW2   = (const float*)d_in[11];
  const float* db2   = (const float*)d_in[12];
  float* out = (float*)d_out;

  const int E  = in_sizes[0] / 2;
  const int N  = in_sizes[2] / EMB;
  const int NB = (N + SCAN_TILE - 1) / SCAN_TILE;

  // workspace layout (weights first: 16B-aligned fragment loads)
  short* W1c  = (short*)d_ws;                   // 2048
  short* W2p  = W1c + 64 * 32;                  // 8192
  short* dW1c = W2p + 8192;                     // 1024
  short* dW2p = dW1c + 64 * 16;                 // 2048
  unsigned int* b2pp = (unsigned int*)(dW2p + 2048);  // 64 u32
  float* ms   = (float*)(b2pp + 64);            // E*8
  float* lat  = ms + (size_t)E * LAT;           // N*8
  int*   deg    = (int*)(lat + (size_t)N * LAT);
  int*   loc    = deg + N;
  int*   offs   = loc + N;
  int*   cursor = offs + N;
  int*   bsum   = cursor + N;                   // NB

  const int blocks_e = (E + 255) / 256;
  const int blocks_n = (N + 255) / 256;

  hipMemsetAsync(deg, 0, (size_t)N * sizeof(int), stream);
  prep_kernel<<<32, 256, 0, stream>>>(ewW1, ewW2, ewb2, dW1, dW2,
                                      W1c, W2p, b2pp, dW1c, dW2p);
  hist_kernel<<<blocks_e, 256, 0, stream>>>(ei, deg, E);
  scan1_kernel<<<NB, SCAN_BLK, 0, stream>>>(deg, loc, bsum, N);
  scan2_kernel<<<1, SCAN_BLK, 0, stream>>>(bsum, NB);
  scan3_kernel<<<blocks_n, 256, 0, stream>>>(loc, bsum, offs, cursor, N);
  enc_mfma_kernel<<<blocks_e, 256, 0, stream>>>(ei, attr, emb, W1c, ewb1, W2p, b2pp,
                                                cursor, ms, E);
  agg_latent_kernel<<<blocks_n, 256, 0, stream>>>(emb, ms, offs, deg, rootW, convb,
                                                  lat, N);
  dec_mfma_kernel<<<blocks_e, 256, 0, stream>>>(ei, lat, dW1c, db1, dW2p, db2, out, E);
}

// Round 8
// 288.220 us; speedup vs baseline: 2.7126x; 1.1448x over previous
//
#include <hip/hip_runtime.h>
#include <hip/hip_bf16.h>

typedef __attribute__((ext_vector_type(8))) short  s16x8;
typedef __attribute__((ext_vector_type(4))) float  f32x4;

constexpr int EMB  = 16;
constexpr int LAT  = 8;
constexpr int EDIM = 32;
constexpr int HID  = 64;

constexpr int SCAN_BLK   = 256;
constexpr int SCAN_ITEMS = 4;
constexpr int SCAN_TILE  = SCAN_BLK * SCAN_ITEMS;  // 1024

__device__ __forceinline__ short f2b(float f) {
  __hip_bfloat16 h = __float2bfloat16(f);
  return __builtin_bit_cast(short, h);
}
__device__ __forceinline__ float asf(unsigned int u) { return __builtin_bit_cast(float, u); }

// ---------------------------------------------------------------------------
// Prep (all bf16):
//  W1c  [64 hid][32 k]  = ew_W1^T                       (GEMM1' A-operand)
//  W2p  GEMM2' A-fragments with k-map g(kt,lh,j)=(kt*2+(j>>2))*16+lh*4+(j&3)
//       and column permutation pi: tile-row r, tile ct2 ->
//       i = 2*ct2 + ((r>>1)&1),  o = 2*(r>>2) + (r&1)   (i*8+o = W2 column)
//  b2pp [lh][ct2*2+ih] packed u32: lo=bf16(b2[i*8+2lh]), hi=bf16(b2[i*8+2lh+1])
//  dW1c [64 hid][16 k] = dec_W1^T
//  dW2p dec GEMM2' A-fragments, identity column map (col = ct2*16 + r)
// ---------------------------------------------------------------------------
__global__ void prep_kernel(const float* __restrict__ W1, const float* __restrict__ W2,
                            const float* __restrict__ b2,
                            const float* __restrict__ dW1, const float* __restrict__ dW2,
                            short* __restrict__ W1c, short* __restrict__ W2p,
                            unsigned int* __restrict__ b2pp,
                            short* __restrict__ dW1c, short* __restrict__ dW2p) {
  int t = blockIdx.x * blockDim.x + threadIdx.x;
  if (t < 64 * 32) { int c = t / 32, k = t % 32; W1c[t] = f2b(W1[k * 64 + c]); }
  if (t < 8192) {
    int ct2 = t >> 10, kt = (t >> 9) & 1, lh = (t >> 7) & 3, r = (t >> 3) & 15, j = t & 7;
    int k = (kt * 2 + (j >> 2)) * 16 + lh * 4 + (j & 3);
    int i = 2 * ct2 + ((r >> 1) & 1);
    int o = 2 * (r >> 2) + (r & 1);
    W2p[t] = f2b(W2[k * 128 + i * 8 + o]);
  }
  if (t < 64) {
    int lh = t >> 4, slot = t & 15;
    int ct2 = slot >> 1, ih = slot & 1;
    int i = 2 * ct2 + ih;
    unsigned int lo = (unsigned short)f2b(b2[i * 8 + 2 * lh]);
    unsigned int hi = (unsigned short)f2b(b2[i * 8 + 2 * lh + 1]);
    b2pp[t] = (hi << 16) | lo;
  }
  if (t < 64 * 16) { int c = t / 16, k = t % 16; dW1c[t] = f2b(dW1[k * 64 + c]); }
  if (t < 2048) {
    int ct2 = t >> 10, kt = (t >> 9) & 1, lh = (t >> 7) & 3, r = (t >> 3) & 15, j = t & 7;
    int k = (kt * 2 + (j >> 2)) * 16 + lh * 4 + (j & 3);
    dW2p[t] = f2b(dW2[k * 32 + ct2 * 16 + r]);
  }
}

// ---------------------------------------------------------------------------
// CSR build: histogram + exclusive scan
// ---------------------------------------------------------------------------
__global__ __launch_bounds__(256) void hist_kernel(const int* __restrict__ ei,
                                                   int* __restrict__ deg, int E) {
  int e = blockIdx.x * blockDim.x + threadIdx.x;
  if (e < E) atomicAdd(&deg[ei[E + e]], 1);
}

__global__ __launch_bounds__(SCAN_BLK) void scan1_kernel(
    const int* __restrict__ deg, int* __restrict__ loc,
    int* __restrict__ bsum, int N) {
  __shared__ int sh[SCAN_BLK];
  int tid  = threadIdx.x;
  int base = blockIdx.x * SCAN_TILE + tid * SCAN_ITEMS;
  int v[SCAN_ITEMS];
  int s = 0;
#pragma unroll
  for (int j = 0; j < SCAN_ITEMS; j++) {
    v[j] = (base + j < N) ? deg[base + j] : 0;
    s += v[j];
  }
  sh[tid] = s;
  __syncthreads();
  for (int off = 1; off < SCAN_BLK; off <<= 1) {
    int t = (tid >= off) ? sh[tid - off] : 0;
    __syncthreads();
    sh[tid] += t;
    __syncthreads();
  }
  int p = sh[tid] - s;
#pragma unroll
  for (int j = 0; j < SCAN_ITEMS; j++) {
    if (base + j < N) loc[base + j] = p;
    p += v[j];
  }
  if (tid == SCAN_BLK - 1) bsum[blockIdx.x] = sh[tid];
}

__global__ __launch_bounds__(SCAN_BLK) void scan2_kernel(int* __restrict__ bsum, int NB) {
  __shared__ int sh[SCAN_BLK];
  int tid  = threadIdx.x;
  int base = tid * SCAN_ITEMS;
  int v[SCAN_ITEMS];
  int s = 0;
#pragma unroll
  for (int j = 0; j < SCAN_ITEMS; j++) {
    v[j] = (base + j < NB) ? bsum[base + j] : 0;
    s += v[j];
  }
  sh[tid] = s;
  __syncthreads();
  for (int off = 1; off < SCAN_BLK; off <<= 1) {
    int t = (tid >= off) ? sh[tid - off] : 0;
    __syncthreads();
    sh[tid] += t;
    __syncthreads();
  }
  int p = sh[tid] - s;
#pragma unroll
  for (int j = 0; j < SCAN_ITEMS; j++) {
    if (base + j < NB) bsum[base + j] = p;
    p += v[j];
  }
}

__global__ __launch_bounds__(256) void scan3_kernel(
    const int* __restrict__ loc, const int* __restrict__ bsum,
    int* __restrict__ offs, int* __restrict__ cursor, int N) {
  int i = blockIdx.x * blockDim.x + threadIdx.x;
  if (i < N) {
    int v = loc[i] + bsum[i / SCAN_TILE];
    offs[i] = v;
    cursor[i] = v;
  }
}

// ---------------------------------------------------------------------------
// Encoder: weights LDS-staged (workgroup-shared), minimal register residency.
// Phase 0 claims the CSR slot (atomic hidden under the MFMA chain) + gathers
// the src embedding. GEMM1' transposed -> H row per lane; GEMM2' transposed
// with pi-permuted cols; lane-local epilogue dot; CSR-slot float2 store.
// ---------------------------------------------------------------------------
__global__ __launch_bounds__(256, 4) void enc_mfma_kernel(
    const int* __restrict__ ei, const float* __restrict__ attr,
    const float* __restrict__ emb,
    const short* __restrict__ W1c, const float* __restrict__ b1,
    const short* __restrict__ W2p, const unsigned int* __restrict__ b2pp,
    int* __restrict__ cursor, float* __restrict__ ms, int E) {
  __shared__ short lds_w1[2048];          // [64 hid][32 k]
  __shared__ short lds_w2[8192];          // GEMM2' fragments
  __shared__ float lds_b1[64];
  __shared__ unsigned int lds_b2[64];

  const int tid = threadIdx.x;
  const int w = tid >> 6, l = tid & 63;
  const int lh = l >> 4, ll = l & 15;
  const int ebase = blockIdx.x * 256 + w * 64;

  // cooperative weight staging (coalesced 16B per thread)
  {
    reinterpret_cast<int4*>(lds_w1)[tid] = reinterpret_cast<const int4*>(W1c)[tid];
#pragma unroll
    for (int i = 0; i < 4; i++)
      reinterpret_cast<int4*>(lds_w2)[i * 256 + tid] =
          reinterpret_cast<const int4*>(W2p)[i * 256 + tid];
    if (tid < 64) lds_b1[tid] = b1[tid];
    if (tid < 64) lds_b2[tid] = b2pp[tid];
  }

  // phase 0: claim CSR slot + gather src embedding, pack to bf16 pairs
  unsigned int xqp[8];
  int mypos = 0;
  {
    int e  = ebase + l;
    int ec = min(e, E - 1);
    int src = ei[ec];
    int tgt = ei[E + ec];
    if (e < E) mypos = atomicAdd(&cursor[tgt], 1);
    const float4* er = reinterpret_cast<const float4*>(emb) + (size_t)src * 4;
    float4 v0 = er[0], v1 = er[1], v2 = er[2], v3 = er[3];
    float xf[16] = {v0.x, v0.y, v0.z, v0.w, v1.x, v1.y, v1.z, v1.w,
                    v2.x, v2.y, v2.z, v2.w, v3.x, v3.y, v3.z, v3.w};
#pragma unroll
    for (int c = 0; c < 8; c++)
      xqp[c] = ((unsigned int)(unsigned short)f2b(xf[2 * c + 1]) << 16) |
               (unsigned int)(unsigned short)f2b(xf[2 * c]);
  }

  __syncthreads();

  const f32x4 z = {0.f, 0.f, 0.f, 0.f};

#pragma unroll
  for (int mt = 0; mt < 4; mt++) {
    // attr row for edge = mt*16 + ll (B-operand of GEMM1')
    int rowA = min(ebase + mt * 16 + ll, E - 1);
    const float4* ap = reinterpret_cast<const float4*>(attr + (size_t)rowA * EDIM + lh * 8);
    float4 a0 = ap[0], a1 = ap[1];
    s16x8 af;
    af[0]=f2b(a0.x); af[1]=f2b(a0.y); af[2]=f2b(a0.z); af[3]=f2b(a0.w);
    af[4]=f2b(a1.x); af[5]=f2b(a1.y); af[6]=f2b(a1.z); af[7]=f2b(a1.w);

    // GEMM1' -> H^T fragments (weights streamed from LDS)
    f32x4 c1t[4];
#pragma unroll
    for (int ct = 0; ct < 4; ct++) {
      s16x8 b1f = *reinterpret_cast<const s16x8*>(lds_w1 + (ct * 16 + ll) * 32 + lh * 8);
      c1t[ct] = __builtin_amdgcn_mfma_f32_16x16x32_bf16(b1f, af, z, 0, 0, 0);
    }

    short hb[4][4];
#pragma unroll
    for (int ct = 0; ct < 4; ct++) {
      float4 bv = *reinterpret_cast<const float4*>(lds_b1 + ct * 16 + lh * 4);  // broadcast
      hb[ct][0] = f2b(fmaxf(c1t[ct][0] + bv.x, 0.f));
      hb[ct][1] = f2b(fmaxf(c1t[ct][1] + bv.y, 0.f));
      hb[ct][2] = f2b(fmaxf(c1t[ct][2] + bv.z, 0.f));
      hb[ct][3] = f2b(fmaxf(c1t[ct][3] + bv.w, 0.f));
    }
    s16x8 a2f0, a2f1;
#pragma unroll
    for (int j = 0; j < 8; j++) a2f0[j] = hb[(j >> 2)][j & 3];
#pragma unroll
    for (int j = 0; j < 8; j++) a2f1[j] = hb[2 + (j >> 2)][j & 3];

    // fetch xe pairs + CSR slot of edge mt*16+ll (from the owning lane)
    const int srcl = mt * 16 + ll;
    unsigned int xs[8];
#pragma unroll
    for (int c = 0; c < 8; c++)
      xs[c] = (unsigned int)__shfl((int)xqp[c], srcl, 64);
    int posv = __shfl(mypos, srcl, 64);

    // GEMM2' + lane-local epilogue with bias (weights + bias from LDS)
    float q0 = 0.f, q1 = 0.f;
#pragma unroll
    for (int ct2 = 0; ct2 < 8; ct2++) {
      s16x8 f0 = *reinterpret_cast<const s16x8*>(lds_w2 + ((ct2 * 2 + 0) * 4 + lh) * 128 + ll * 8);
      s16x8 f1 = *reinterpret_cast<const s16x8*>(lds_w2 + ((ct2 * 2 + 1) * 4 + lh) * 128 + ll * 8);
      f32x4 c2 = __builtin_amdgcn_mfma_f32_16x16x32_bf16(f0, a2f0, z, 0, 0, 0);
      c2 = __builtin_amdgcn_mfma_f32_16x16x32_bf16(f1, a2f1, c2, 0, 0, 0);
      uint2 pp = *reinterpret_cast<const uint2*>(lds_b2 + lh * 16 + 2 * ct2);  // broadcast
      float b00 = asf(pp.x << 16), b01 = asf(pp.x & 0xffff0000u);
      float b10 = asf(pp.y << 16), b11 = asf(pp.y & 0xffff0000u);
      float xv0 = asf(xs[ct2] << 16);          // xe[2*ct2]
      float xv1 = asf(xs[ct2] & 0xffff0000u);  // xe[2*ct2+1]
      q0 = fmaf(xv0, c2[0] + b00, q0);
      q1 = fmaf(xv0, c2[1] + b01, q1);
      q0 = fmaf(xv1, c2[2] + b10, q0);
      q1 = fmaf(xv1, c2[3] + b11, q1);
    }
    int e = ebase + mt * 16 + ll;
    if (e < E)
      *reinterpret_cast<float2*>(ms + (size_t)posv * LAT + 2 * lh) = make_float2(q0, q1);
  }
}

// ---------------------------------------------------------------------------
// Aggregate contiguous CSR message rows + root weight -> latent
// ---------------------------------------------------------------------------
__global__ __launch_bounds__(256) void agg_latent_kernel(
    const float* __restrict__ emb, const float* __restrict__ ms,
    const int* __restrict__ offs, const int* __restrict__ deg,
    const float* __restrict__ rootW, const float* __restrict__ convb,
    float* __restrict__ latent, int N) {
  int n = blockIdx.x * blockDim.x + threadIdx.x;
  if (n >= N) return;
  int start = offs[n];
  int d = deg[n];

  float r[LAT];
#pragma unroll
  for (int o = 0; o < LAT; o++) r[o] = 0.f;

  const float4* mp = reinterpret_cast<const float4*>(ms);
  for (int j = 0; j < d; j++) {
    float4 a = mp[(size_t)(start + j) * 2];
    float4 b = mp[(size_t)(start + j) * 2 + 1];
    r[0] += a.x; r[1] += a.y; r[2] += a.z; r[3] += a.w;
    r[4] += b.x; r[5] += b.y; r[6] += b.z; r[7] += b.w;
  }

  float inv = 1.f / fmaxf((float)d, 1.f);
#pragma unroll
  for (int o = 0; o < LAT; o++) r[o] = fmaf(r[o], inv, convb[o]);

  float x[EMB];
  const float4* np4 = reinterpret_cast<const float4*>(emb) + (size_t)n * (EMB / 4);
#pragma unroll
  for (int i = 0; i < EMB / 4; i++) {
    float4 v = np4[i];
    x[4 * i + 0] = v.x; x[4 * i + 1] = v.y; x[4 * i + 2] = v.z; x[4 * i + 3] = v.w;
  }
#pragma unroll
  for (int i = 0; i < EMB; i++)
#pragma unroll
    for (int o = 0; o < LAT; o++) r[o] = fmaf(x[i], rootW[i * LAT + o], r[o]);

  float4* lp = reinterpret_cast<float4*>(latent) + (size_t)n * 2;
  lp[0] = make_float4(r[0], r[1], r[2], r[3]);
  lp[1] = make_float4(r[4], r[5], r[6], r[7]);
}

// ---------------------------------------------------------------------------
// Decoder: weights LDS-staged (with K-pad zeros materialized); per-mt latent
// gather; transposed GEMM2 -> coalesced float4 stores.
// ---------------------------------------------------------------------------
__global__ __launch_bounds__(256, 4) void dec_mfma_kernel(
    const int* __restrict__ ei, const float* __restrict__ lat,
    const short* __restrict__ dW1c, const float* __restrict__ db1,
    const short* __restrict__ dW2p, const float* __restrict__ db2,
    float* __restrict__ out, int E) {
  __shared__ short lds_w1[2048];   // [64 hid][32 k], k>=16 zeroed
  __shared__ short lds_w2[2048];   // dec GEMM2' fragments
  __shared__ float lds_b1[64];
  __shared__ float lds_b2[32];

  const int tid = threadIdx.x;
  const int w = tid >> 6, l = tid & 63;
  const int lh = l >> 4, ll = l & 15;
  const int ebase = blockIdx.x * 256 + w * 64;

  // staging: dW1c is [64][16]; expand to [64][32] with zero upper K half
  {
    if (tid < 128) {
      int4 v = reinterpret_cast<const int4*>(dW1c)[tid];
      int hid = tid >> 1, kb = (tid & 1) * 8;
      *reinterpret_cast<int4*>(lds_w1 + hid * 32 + kb) = v;
      *reinterpret_cast<int4*>(lds_w1 + hid * 32 + 16 + kb) = make_int4(0, 0, 0, 0);
    }
    reinterpret_cast<int4*>(lds_w2)[tid] = reinterpret_cast<const int4*>(dW2p)[tid];
    if (tid < 64) lds_b1[tid] = db1[tid];
    if (tid < 32) lds_b2[tid] = db2[tid];
  }
  __syncthreads();

  const f32x4 z = {0.f, 0.f, 0.f, 0.f};

#pragma unroll
  for (int mt = 0; mt < 4; mt++) {
    // latent halves: lh=0 -> src, lh=1 -> tgt, lh>=2 zero pad (k 16..31)
    s16x8 af = (s16x8){0, 0, 0, 0, 0, 0, 0, 0};
    if (lh < 2) {
      int rowA = min(ebase + mt * 16 + ll, E - 1);
      int node = ei[(lh == 0 ? 0 : E) + rowA];
      const float4* lp = reinterpret_cast<const float4*>(lat + (size_t)node * LAT);
      float4 p0 = lp[0], p1 = lp[1];
      af[0]=f2b(p0.x); af[1]=f2b(p0.y); af[2]=f2b(p0.z); af[3]=f2b(p0.w);
      af[4]=f2b(p1.x); af[5]=f2b(p1.y); af[6]=f2b(p1.z); af[7]=f2b(p1.w);
    }

    f32x4 c1t[4];
#pragma unroll
    for (int ct = 0; ct < 4; ct++) {
      s16x8 b1f = *reinterpret_cast<const s16x8*>(lds_w1 + (ct * 16 + ll) * 32 + lh * 8);
      c1t[ct] = __builtin_amdgcn_mfma_f32_16x16x32_bf16(b1f, af, z, 0, 0, 0);
    }

    short hb[4][4];
#pragma unroll
    for (int ct = 0; ct < 4; ct++) {
      float4 bv = *reinterpret_cast<const float4*>(lds_b1 + ct * 16 + lh * 4);  // broadcast
      hb[ct][0] = f2b(fmaxf(c1t[ct][0] + bv.x, 0.f));
      hb[ct][1] = f2b(fmaxf(c1t[ct][1] + bv.y, 0.f));
      hb[ct][2] = f2b(fmaxf(c1t[ct][2] + bv.z, 0.f));
      hb[ct][3] = f2b(fmaxf(c1t[ct][3] + bv.w, 0.f));
    }
    s16x8 a2f0, a2f1;
#pragma unroll
    for (int j = 0; j < 8; j++) a2f0[j] = hb[(j >> 2)][j & 3];
#pragma unroll
    for (int j = 0; j < 8; j++) a2f1[j] = hb[2 + (j >> 2)][j & 3];

    int e = ebase + mt * 16 + ll;
#pragma unroll
    for (int ct2 = 0; ct2 < 2; ct2++) {
      s16x8 f0 = *reinterpret_cast<const s16x8*>(lds_w2 + ((ct2 * 2 + 0) * 4 + lh) * 128 + ll * 8);
      s16x8 f1 = *reinterpret_cast<const s16x8*>(lds_w2 + ((ct2 * 2 + 1) * 4 + lh) * 128 + ll * 8);
      f32x4 c2 = __builtin_amdgcn_mfma_f32_16x16x32_bf16(f0, a2f0, z, 0, 0, 0);
      c2 = __builtin_amdgcn_mfma_f32_16x16x32_bf16(f1, a2f1, c2, 0, 0, 0);
      float4 bv = *reinterpret_cast<const float4*>(lds_b2 + ct2 * 16 + lh * 4);  // broadcast
      if (e < E)
        *reinterpret_cast<float4*>(out + (size_t)e * EDIM + ct2 * 16 + lh * 4) =
            make_float4(c2[0] + bv.x, c2[1] + bv.y, c2[2] + bv.z, c2[3] + bv.w);
    }
  }
}

// ---------------------------------------------------------------------------
extern "C" void kernel_launch(void* const* d_in, const int* in_sizes, int n_in,
                              void* d_out, int out_size, void* d_ws, size_t ws_size,
                              hipStream_t stream) {
  const int*   ei    = (const int*)  d_in[0];
  const float* attr  = (const float*)d_in[1];
  const float* emb   = (const float*)d_in[2];
  const float* ewW1  = (const float*)d_in[3];
  const float* ewb1  = (const float*)d_in[4];
  const float* ewW2  = (const float*)d_in[5];
  const float* ewb2  = (const float*)d_in[6];
  const float* rootW = (const float*)d_in[7];
  const float* convb = (const float*)d_in[8];
  const float* dW1   = (const float*)d_in[9];
  const float* db1   = (const float*)d_in[10];
  const float* dW2   = (const float*)d_in[11];
  const float* db2   = (const float*)d_in[12];
  float* out = (float*)d_out;

  const int E  = in_sizes[0] / 2;
  const int N  = in_sizes[2] / EMB;
  const int NB = (N + SCAN_TILE - 1) / SCAN_TILE;

  // workspace layout (weights first: 16B-aligned fragment loads)
  short* W1c  = (short*)d_ws;                   // 2048 shorts
  short* W2p  = W1c + 64 * 32;                  // 8192
  short* dW1c = W2p + 8192;                     // 1024
  short* dW2p = dW1c + 64 * 16;                 // 2048
  unsigned int* b2pp = (unsigned int*)(dW2p + 2048);  // 64 u32
  float* ms   = (float*)(b2pp + 64);            // E*8
  float* lat  = ms + (size_t)E * LAT;           // N*8
  int*   deg    = (int*)(lat + (size_t)N * LAT);
  int*   loc    = deg + N;
  int*   offs   = loc + N;
  int*   cursor = offs + N;
  int*   bsum   = cursor + N;                   // NB

  const int blocks_e = (E + 255) / 256;
  const int blocks_n = (N + 255) / 256;

  hipMemsetAsync(deg, 0, (size_t)N * sizeof(int), stream);
  prep_kernel<<<32, 256, 0, stream>>>(ewW1, ewW2, ewb2, dW1, dW2,
                                      W1c, W2p, b2pp, dW1c, dW2p);
  hist_kernel<<<blocks_e, 256, 0, stream>>>(ei, deg, E);
  scan1_kernel<<<NB, SCAN_BLK, 0, stream>>>(deg, loc, bsum, N);
  scan2_kernel<<<1, SCAN_BLK, 0, stream>>>(bsum, NB);
  scan3_kernel<<<blocks_n, 256, 0, stream>>>(loc, bsum, offs, cursor, N);
  enc_mfma_kernel<<<blocks_e, 256, 0, stream>>>(ei, attr, emb, W1c, ewb1, W2p, b2pp,
                                                cursor, ms, E);
  agg_latent_kernel<<<blocks_n, 256, 0, stream>>>(emb, ms, offs, deg, rootW, convb,
                                                  lat, N);
  dec_mfma_kernel<<<blocks_e, 256, 0, stream>>>(ei, lat, dW1c, db1, dW2p, db2, out, E);
}

// Round 9
// 268.874 us; speedup vs baseline: 2.9078x; 1.0720x over previous
//
#include <hip/hip_runtime.h>
#include <hip/hip_bf16.h>

typedef __attribute__((ext_vector_type(8))) short  s16x8;
typedef __attribute__((ext_vector_type(4))) float  f32x4;

constexpr int EMB  = 16;
constexpr int LAT  = 8;
constexpr int EDIM = 32;
constexpr int HID  = 64;

constexpr int SCAN_BLK   = 256;
constexpr int SCAN_ITEMS = 4;
constexpr int SCAN_TILE  = SCAN_BLK * SCAN_ITEMS;  // 1024

__device__ __forceinline__ short f2b(float f) {
  __hip_bfloat16 h = __float2bfloat16(f);
  return __builtin_bit_cast(short, h);
}
__device__ __forceinline__ float asf(unsigned int u) { return __builtin_bit_cast(float, u); }
__device__ __forceinline__ unsigned int pk2(float lo, float hi) {
  return ((unsigned int)(unsigned short)f2b(hi) << 16) |
         (unsigned int)(unsigned short)f2b(lo);
}

// ---------------------------------------------------------------------------
// Prep (all bf16):
//  W1c  [64 hid][32 k]  = ew_W1^T                       (GEMM1' A-operand)
//  W2p  GEMM2' A-fragments with k-map g(kt,lh,j)=(kt*2+(j>>2))*16+lh*4+(j&3)
//       and column permutation pi: tile-row r, tile ct2 ->
//       i = 2*ct2 + ((r>>1)&1),  o = 2*(r>>2) + (r&1)   (i*8+o = W2 column)
//  b2pp [lh][ct2*2+ih] packed u32: lo=bf16(b2[i*8+2lh]), hi=bf16(b2[i*8+2lh+1])
//  dW1c [64 hid][16 k] = dec_W1^T
//  dW2p dec GEMM2' A-fragments, identity column map (col = ct2*16 + r)
// ---------------------------------------------------------------------------
__global__ void prep_kernel(const float* __restrict__ W1, const float* __restrict__ W2,
                            const float* __restrict__ b2,
                            const float* __restrict__ dW1, const float* __restrict__ dW2,
                            short* __restrict__ W1c, short* __restrict__ W2p,
                            unsigned int* __restrict__ b2pp,
                            short* __restrict__ dW1c, short* __restrict__ dW2p) {
  int t = blockIdx.x * blockDim.x + threadIdx.x;
  if (t < 64 * 32) { int c = t / 32, k = t % 32; W1c[t] = f2b(W1[k * 64 + c]); }
  if (t < 8192) {
    int ct2 = t >> 10, kt = (t >> 9) & 1, lh = (t >> 7) & 3, r = (t >> 3) & 15, j = t & 7;
    int k = (kt * 2 + (j >> 2)) * 16 + lh * 4 + (j & 3);
    int i = 2 * ct2 + ((r >> 1) & 1);
    int o = 2 * (r >> 2) + (r & 1);
    W2p[t] = f2b(W2[k * 128 + i * 8 + o]);
  }
  if (t < 64) {
    int lh = t >> 4, slot = t & 15;
    int ct2 = slot >> 1, ih = slot & 1;
    int i = 2 * ct2 + ih;
    unsigned int lo = (unsigned short)f2b(b2[i * 8 + 2 * lh]);
    unsigned int hi = (unsigned short)f2b(b2[i * 8 + 2 * lh + 1]);
    b2pp[t] = (hi << 16) | lo;
  }
  if (t < 64 * 16) { int c = t / 16, k = t % 16; dW1c[t] = f2b(dW1[k * 64 + c]); }
  if (t < 2048) {
    int ct2 = t >> 10, kt = (t >> 9) & 1, lh = (t >> 7) & 3, r = (t >> 3) & 15, j = t & 7;
    int k = (kt * 2 + (j >> 2)) * 16 + lh * 4 + (j & 3);
    dW2p[t] = f2b(dW2[k * 32 + ct2 * 16 + r]);
  }
}

// ---------------------------------------------------------------------------
// CSR build: histogram + exclusive scan
// ---------------------------------------------------------------------------
__global__ __launch_bounds__(256) void hist_kernel(const int* __restrict__ ei,
                                                   int* __restrict__ deg, int E) {
  int e = blockIdx.x * blockDim.x + threadIdx.x;
  if (e < E) atomicAdd(&deg[ei[E + e]], 1);
}

__global__ __launch_bounds__(SCAN_BLK) void scan1_kernel(
    const int* __restrict__ deg, int* __restrict__ loc,
    int* __restrict__ bsum, int N) {
  __shared__ int sh[SCAN_BLK];
  int tid  = threadIdx.x;
  int base = blockIdx.x * SCAN_TILE + tid * SCAN_ITEMS;
  int v[SCAN_ITEMS];
  int s = 0;
#pragma unroll
  for (int j = 0; j < SCAN_ITEMS; j++) {
    v[j] = (base + j < N) ? deg[base + j] : 0;
    s += v[j];
  }
  sh[tid] = s;
  __syncthreads();
  for (int off = 1; off < SCAN_BLK; off <<= 1) {
    int t = (tid >= off) ? sh[tid - off] : 0;
    __syncthreads();
    sh[tid] += t;
    __syncthreads();
  }
  int p = sh[tid] - s;
#pragma unroll
  for (int j = 0; j < SCAN_ITEMS; j++) {
    if (base + j < N) loc[base + j] = p;
    p += v[j];
  }
  if (tid == SCAN_BLK - 1) bsum[blockIdx.x] = sh[tid];
}

__global__ __launch_bounds__(SCAN_BLK) void scan2_kernel(int* __restrict__ bsum, int NB) {
  __shared__ int sh[SCAN_BLK];
  int tid  = threadIdx.x;
  int base = tid * SCAN_ITEMS;
  int v[SCAN_ITEMS];
  int s = 0;
#pragma unroll
  for (int j = 0; j < SCAN_ITEMS; j++) {
    v[j] = (base + j < NB) ? bsum[base + j] : 0;
    s += v[j];
  }
  sh[tid] = s;
  __syncthreads();
  for (int off = 1; off < SCAN_BLK; off <<= 1) {
    int t = (tid >= off) ? sh[tid - off] : 0;
    __syncthreads();
    sh[tid] += t;
    __syncthreads();
  }
  int p = sh[tid] - s;
#pragma unroll
  for (int j = 0; j < SCAN_ITEMS; j++) {
    if (base + j < NB) bsum[base + j] = p;
    p += v[j];
  }
}

__global__ __launch_bounds__(256) void scan3_kernel(
    const int* __restrict__ loc, const int* __restrict__ bsum,
    int* __restrict__ offs, int* __restrict__ cursor, int N) {
  int i = blockIdx.x * blockDim.x + threadIdx.x;
  if (i < N) {
    int v = loc[i] + bsum[i / SCAN_TILE];
    offs[i] = v;
    cursor[i] = v;
  }
}

// ---------------------------------------------------------------------------
// Encoder: weights LDS-staged, attr prefetched to bf16 fragments, bf16
// message scatter (16B/message). Phase 0 claims the CSR slot (atomic hidden
// under the MFMA chain) + gathers the src embedding.
// ---------------------------------------------------------------------------
__global__ __launch_bounds__(256, 3) void enc_mfma_kernel(
    const int* __restrict__ ei, const float* __restrict__ attr,
    const float* __restrict__ emb,
    const short* __restrict__ W1c, const float* __restrict__ b1,
    const short* __restrict__ W2p, const unsigned int* __restrict__ b2pp,
    int* __restrict__ cursor, short* __restrict__ ms, int E) {
  __shared__ short lds_w1[2048];          // [64 hid][32 k]
  __shared__ short lds_w2[8192];          // GEMM2' fragments
  __shared__ float lds_b1[64];
  __shared__ unsigned int lds_b2[64];

  const int tid = threadIdx.x;
  const int w = tid >> 6, l = tid & 63;
  const int lh = l >> 4, ll = l & 15;
  const int ebase = blockIdx.x * 256 + w * 64;

  // cooperative weight staging (coalesced 16B per thread)
  {
    reinterpret_cast<int4*>(lds_w1)[tid] = reinterpret_cast<const int4*>(W1c)[tid];
#pragma unroll
    for (int i = 0; i < 4; i++)
      reinterpret_cast<int4*>(lds_w2)[i * 256 + tid] =
          reinterpret_cast<const int4*>(W2p)[i * 256 + tid];
    if (tid < 64) lds_b1[tid] = b1[tid];
    if (tid < 64) lds_b2[tid] = b2pp[tid];
  }

  // phase 0: claim CSR slot + gather src embedding, pack to bf16 pairs
  unsigned int xqp[8];
  int mypos = 0;
  {
    int e  = ebase + l;
    int ec = min(e, E - 1);
    int src = ei[ec];
    int tgt = ei[E + ec];
    if (e < E) mypos = atomicAdd(&cursor[tgt], 1);
    const float4* er = reinterpret_cast<const float4*>(emb) + (size_t)src * 4;
    float4 v0 = er[0], v1 = er[1], v2 = er[2], v3 = er[3];
    xqp[0] = pk2(v0.x, v0.y); xqp[1] = pk2(v0.z, v0.w);
    xqp[2] = pk2(v1.x, v1.y); xqp[3] = pk2(v1.z, v1.w);
    xqp[4] = pk2(v2.x, v2.y); xqp[5] = pk2(v2.z, v2.w);
    xqp[6] = pk2(v3.x, v3.y); xqp[7] = pk2(v3.z, v3.w);
  }

  // prefetch attr rows for all 4 tiles, convert to bf16 fragments (16 regs)
  s16x8 afs[4];
#pragma unroll
  for (int mt = 0; mt < 4; mt++) {
    int rowA = min(ebase + mt * 16 + ll, E - 1);
    const float4* ap = reinterpret_cast<const float4*>(attr + (size_t)rowA * EDIM + lh * 8);
    float4 a0 = ap[0], a1 = ap[1];
    afs[mt][0]=f2b(a0.x); afs[mt][1]=f2b(a0.y); afs[mt][2]=f2b(a0.z); afs[mt][3]=f2b(a0.w);
    afs[mt][4]=f2b(a1.x); afs[mt][5]=f2b(a1.y); afs[mt][6]=f2b(a1.z); afs[mt][7]=f2b(a1.w);
  }

  __syncthreads();

  const f32x4 z = {0.f, 0.f, 0.f, 0.f};

#pragma unroll
  for (int mt = 0; mt < 4; mt++) {
    // GEMM1' -> H^T fragments (weights streamed from LDS)
    f32x4 c1t[4];
#pragma unroll
    for (int ct = 0; ct < 4; ct++) {
      s16x8 b1f = *reinterpret_cast<const s16x8*>(lds_w1 + (ct * 16 + ll) * 32 + lh * 8);
      c1t[ct] = __builtin_amdgcn_mfma_f32_16x16x32_bf16(b1f, afs[mt], z, 0, 0, 0);
    }

    short hb[4][4];
#pragma unroll
    for (int ct = 0; ct < 4; ct++) {
      float4 bv = *reinterpret_cast<const float4*>(lds_b1 + ct * 16 + lh * 4);  // broadcast
      hb[ct][0] = f2b(fmaxf(c1t[ct][0] + bv.x, 0.f));
      hb[ct][1] = f2b(fmaxf(c1t[ct][1] + bv.y, 0.f));
      hb[ct][2] = f2b(fmaxf(c1t[ct][2] + bv.z, 0.f));
      hb[ct][3] = f2b(fmaxf(c1t[ct][3] + bv.w, 0.f));
    }
    s16x8 a2f0, a2f1;
#pragma unroll
    for (int j = 0; j < 8; j++) a2f0[j] = hb[(j >> 2)][j & 3];
#pragma unroll
    for (int j = 0; j < 8; j++) a2f1[j] = hb[2 + (j >> 2)][j & 3];

    // fetch xe pairs + CSR slot of edge mt*16+ll (from the owning lane)
    const int srcl = mt * 16 + ll;
    unsigned int xs[8];
#pragma unroll
    for (int c = 0; c < 8; c++)
      xs[c] = (unsigned int)__shfl((int)xqp[c], srcl, 64);
    int posv = __shfl(mypos, srcl, 64);

    // GEMM2' + lane-local epilogue with bias (weights + bias from LDS)
    float q0 = 0.f, q1 = 0.f;
#pragma unroll
    for (int ct2 = 0; ct2 < 8; ct2++) {
      s16x8 f0 = *reinterpret_cast<const s16x8*>(lds_w2 + ((ct2 * 2 + 0) * 4 + lh) * 128 + ll * 8);
      s16x8 f1 = *reinterpret_cast<const s16x8*>(lds_w2 + ((ct2 * 2 + 1) * 4 + lh) * 128 + ll * 8);
      f32x4 c2 = __builtin_amdgcn_mfma_f32_16x16x32_bf16(f0, a2f0, z, 0, 0, 0);
      c2 = __builtin_amdgcn_mfma_f32_16x16x32_bf16(f1, a2f1, c2, 0, 0, 0);
      uint2 pp = *reinterpret_cast<const uint2*>(lds_b2 + lh * 16 + 2 * ct2);  // broadcast
      float b00 = asf(pp.x << 16), b01 = asf(pp.x & 0xffff0000u);
      float b10 = asf(pp.y << 16), b11 = asf(pp.y & 0xffff0000u);
      float xv0 = asf(xs[ct2] << 16);          // xe[2*ct2]
      float xv1 = asf(xs[ct2] & 0xffff0000u);  // xe[2*ct2+1]
      q0 = fmaf(xv0, c2[0] + b00, q0);
      q1 = fmaf(xv0, c2[1] + b01, q1);
      q0 = fmaf(xv1, c2[2] + b10, q0);
      q1 = fmaf(xv1, c2[3] + b11, q1);
    }
    // bf16 message store: lane writes 4B of the 16B message at its CSR slot
    int e = ebase + mt * 16 + ll;
    if (e < E)
      *reinterpret_cast<unsigned int*>(ms + (size_t)posv * LAT + 2 * lh) = pk2(q0, q1);
  }
}

// ---------------------------------------------------------------------------
// Aggregate contiguous CSR bf16 message rows + root weight -> latent
// ---------------------------------------------------------------------------
__global__ __launch_bounds__(256) void agg_latent_kernel(
    const float* __restrict__ emb, const short* __restrict__ ms,
    const int* __restrict__ offs, const int* __restrict__ deg,
    const float* __restrict__ rootW, const float* __restrict__ convb,
    float* __restrict__ latent, int N) {
  int n = blockIdx.x * blockDim.x + threadIdx.x;
  if (n >= N) return;
  int start = offs[n];
  int d = deg[n];

  float r[LAT];
#pragma unroll
  for (int o = 0; o < LAT; o++) r[o] = 0.f;

  const uint4* mp = reinterpret_cast<const uint4*>(ms);
  for (int j = 0; j < d; j++) {
    uint4 v = mp[(size_t)(start + j)];
    r[0] += asf(v.x << 16); r[1] += asf(v.x & 0xffff0000u);
    r[2] += asf(v.y << 16); r[3] += asf(v.y & 0xffff0000u);
    r[4] += asf(v.z << 16); r[5] += asf(v.z & 0xffff0000u);
    r[6] += asf(v.w << 16); r[7] += asf(v.w & 0xffff0000u);
  }

  float inv = 1.f / fmaxf((float)d, 1.f);
#pragma unroll
  for (int o = 0; o < LAT; o++) r[o] = fmaf(r[o], inv, convb[o]);

  float x[EMB];
  const float4* np4 = reinterpret_cast<const float4*>(emb) + (size_t)n * (EMB / 4);
#pragma unroll
  for (int i = 0; i < EMB / 4; i++) {
    float4 v = np4[i];
    x[4 * i + 0] = v.x; x[4 * i + 1] = v.y; x[4 * i + 2] = v.z; x[4 * i + 3] = v.w;
  }
#pragma unroll
  for (int i = 0; i < EMB; i++)
#pragma unroll
    for (int o = 0; o < LAT; o++) r[o] = fmaf(x[i], rootW[i * LAT + o], r[o]);

  float4* lp = reinterpret_cast<float4*>(latent) + (size_t)n * 2;
  lp[0] = make_float4(r[0], r[1], r[2], r[3]);
  lp[1] = make_float4(r[4], r[5], r[6], r[7]);
}

// ---------------------------------------------------------------------------
// Decoder: weights LDS-staged (with K-pad zeros materialized); per-mt latent
// gather; transposed GEMM2 -> coalesced float4 stores.
// ---------------------------------------------------------------------------
__global__ __launch_bounds__(256, 4) void dec_mfma_kernel(
    const int* __restrict__ ei, const float* __restrict__ lat,
    const short* __restrict__ dW1c, const float* __restrict__ db1,
    const short* __restrict__ dW2p, const float* __restrict__ db2,
    float* __restrict__ out, int E) {
  __shared__ short lds_w1[2048];   // [64 hid][32 k], k>=16 zeroed
  __shared__ short lds_w2[2048];   // dec GEMM2' fragments
  __shared__ float lds_b1[64];
  __shared__ float lds_b2[32];

  const int tid = threadIdx.x;
  const int w = tid >> 6, l = tid & 63;
  const int lh = l >> 4, ll = l & 15;
  const int ebase = blockIdx.x * 256 + w * 64;

  // staging: dW1c is [64][16]; expand to [64][32] with zero upper K half
  {
    if (tid < 128) {
      int4 v = reinterpret_cast<const int4*>(dW1c)[tid];
      int hid = tid >> 1, kb = (tid & 1) * 8;
      *reinterpret_cast<int4*>(lds_w1 + hid * 32 + kb) = v;
      *reinterpret_cast<int4*>(lds_w1 + hid * 32 + 16 + kb) = make_int4(0, 0, 0, 0);
    }
    reinterpret_cast<int4*>(lds_w2)[tid] = reinterpret_cast<const int4*>(dW2p)[tid];
    if (tid < 64) lds_b1[tid] = db1[tid];
    if (tid < 32) lds_b2[tid] = db2[tid];
  }
  __syncthreads();

  const f32x4 z = {0.f, 0.f, 0.f, 0.f};

#pragma unroll
  for (int mt = 0; mt < 4; mt++) {
    // latent halves: lh=0 -> src, lh=1 -> tgt, lh>=2 zero pad (k 16..31)
    s16x8 af = (s16x8){0, 0, 0, 0, 0, 0, 0, 0};
    if (lh < 2) {
      int rowA = min(ebase + mt * 16 + ll, E - 1);
      int node = ei[(lh == 0 ? 0 : E) + rowA];
      const float4* lp = reinterpret_cast<const float4*>(lat + (size_t)node * LAT);
      float4 p0 = lp[0], p1 = lp[1];
      af[0]=f2b(p0.x); af[1]=f2b(p0.y); af[2]=f2b(p0.z); af[3]=f2b(p0.w);
      af[4]=f2b(p1.x); af[5]=f2b(p1.y); af[6]=f2b(p1.z); af[7]=f2b(p1.w);
    }

    f32x4 c1t[4];
#pragma unroll
    for (int ct = 0; ct < 4; ct++) {
      s16x8 b1f = *reinterpret_cast<const s16x8*>(lds_w1 + (ct * 16 + ll) * 32 + lh * 8);
      c1t[ct] = __builtin_amdgcn_mfma_f32_16x16x32_bf16(b1f, af, z, 0, 0, 0);
    }

    short hb[4][4];
#pragma unroll
    for (int ct = 0; ct < 4; ct++) {
      float4 bv = *reinterpret_cast<const float4*>(lds_b1 + ct * 16 + lh * 4);  // broadcast
      hb[ct][0] = f2b(fmaxf(c1t[ct][0] + bv.x, 0.f));
      hb[ct][1] = f2b(fmaxf(c1t[ct][1] + bv.y, 0.f));
      hb[ct][2] = f2b(fmaxf(c1t[ct][2] + bv.z, 0.f));
      hb[ct][3] = f2b(fmaxf(c1t[ct][3] + bv.w, 0.f));
    }
    s16x8 a2f0, a2f1;
#pragma unroll
    for (int j = 0; j < 8; j++) a2f0[j] = hb[(j >> 2)][j & 3];
#pragma unroll
    for (int j = 0; j < 8; j++) a2f1[j] = hb[2 + (j >> 2)][j & 3];

    int e = ebase + mt * 16 + ll;
#pragma unroll
    for (int ct2 = 0; ct2 < 2; ct2++) {
      s16x8 f0 = *reinterpret_cast<const s16x8*>(lds_w2 + ((ct2 * 2 + 0) * 4 + lh) * 128 + ll * 8);
      s16x8 f1 = *reinterpret_cast<const s16x8*>(lds_w2 + ((ct2 * 2 + 1) * 4 + lh) * 128 + ll * 8);
      f32x4 c2 = __builtin_amdgcn_mfma_f32_16x16x32_bf16(f0, a2f0, z, 0, 0, 0);
      c2 = __builtin_amdgcn_mfma_f32_16x16x32_bf16(f1, a2f1, c2, 0, 0, 0);
      float4 bv = *reinterpret_cast<const float4*>(lds_b2 + ct2 * 16 + lh * 4);  // broadcast
      if (e < E)
        *reinterpret_cast<float4*>(out + (size_t)e * EDIM + ct2 * 16 + lh * 4) =
            make_float4(c2[0] + bv.x, c2[1] + bv.y, c2[2] + bv.z, c2[3] + bv.w);
    }
  }
}

// ---------------------------------------------------------------------------
extern "C" void kernel_launch(void* const* d_in, const int* in_sizes, int n_in,
                              void* d_out, int out_size, void* d_ws, size_t ws_size,
                              hipStream_t stream) {
  const int*   ei    = (const int*)  d_in[0];
  const float* attr  = (const float*)d_in[1];
  const float* emb   = (const float*)d_in[2];
  const float* ewW1  = (const float*)d_in[3];
  const float* ewb1  = (const float*)d_in[4];
  const float* ewW2  = (const float*)d_in[5];
  const float* ewb2  = (const float*)d_in[6];
  const float* rootW = (const float*)d_in[7];
  const float* convb = (const float*)d_in[8];
  const float* dW1   = (const float*)d_in[9];
  const float* db1   = (const float*)d_in[10];
  const float* dW2   = (const float*)d_in[11];
  const float* db2   = (const float*)d_in[12];
  float* out = (float*)d_out;

  const int E  = in_sizes[0] / 2;
  const int N  = in_sizes[2] / EMB;
  const int NB = (N + SCAN_TILE - 1) / SCAN_TILE;

  // workspace layout (weights first: 16B-aligned fragment loads)
  short* W1c  = (short*)d_ws;                   // 2048 shorts
  short* W2p  = W1c + 64 * 32;                  // 8192
  short* dW1c = W2p + 8192;                     // 1024
  short* dW2p = dW1c + 64 * 16;                 // 2048
  unsigned int* b2pp = (unsigned int*)(dW2p + 2048);  // 64 u32
  short* ms   = (short*)(b2pp + 64);            // E*8 bf16 (16B/message)
  float* lat  = (float*)(ms + (size_t)E * LAT); // N*8
  int*   deg    = (int*)(lat + (size_t)N * LAT);
  int*   loc    = deg + N;
  int*   offs   = loc + N;
  int*   cursor = offs + N;
  int*   bsum   = cursor + N;                   // NB

  const int blocks_e = (E + 255) / 256;
  const int blocks_n = (N + 255) / 256;

  hipMemsetAsync(deg, 0, (size_t)N * sizeof(int), stream);
  prep_kernel<<<32, 256, 0, stream>>>(ewW1, ewW2, ewb2, dW1, dW2,
                                      W1c, W2p, b2pp, dW1c, dW2p);
  hist_kernel<<<blocks_e, 256, 0, stream>>>(ei, deg, E);
  scan1_kernel<<<NB, SCAN_BLK, 0, stream>>>(deg, loc, bsum, N);
  scan2_kernel<<<1, SCAN_BLK, 0, stream>>>(bsum, NB);
  scan3_kernel<<<blocks_n, 256, 0, stream>>>(loc, bsum, offs, cursor, N);
  enc_mfma_kernel<<<blocks_e, 256, 0, stream>>>(ei, attr, emb, W1c, ewb1, W2p, b2pp,
                                                cursor, ms, E);
  agg_latent_kernel<<<blocks_n, 256, 0, stream>>>(emb, ms, offs, deg, rootW, convb,
                                                  lat, N);
  dec_mfma_kernel<<<blocks_e, 256, 0, stream>>>(ei, lat, dW1c, db1, dW2p, db2, out, E);
}

// Round 10
// 220.740 us; speedup vs baseline: 3.5419x; 1.2181x over previous
//
#include <hip/hip_runtime.h>
#include <hip/hip_bf16.h>

typedef __attribute__((ext_vector_type(8))) short  s16x8;
typedef __attribute__((ext_vector_type(4))) float  f32x4;

constexpr int EMB  = 16;
constexpr int LAT  = 8;
constexpr int EDIM = 32;
constexpr int HID  = 64;

constexpr int BSHIFT = 7;                 // 128 nodes per bucket
constexpr int BNODES = 1 << BSHIFT;
constexpr int PCHUNK = 8192;              // edges per partition block

__device__ __forceinline__ short f2b(float f) {
  __hip_bfloat16 h = __float2bfloat16(f);
  return __builtin_bit_cast(short, h);
}
__device__ __forceinline__ float asf(unsigned int u) { return __builtin_bit_cast(float, u); }
__device__ __forceinline__ unsigned int pk2(float lo, float hi) {
  return ((unsigned int)(unsigned short)f2b(hi) << 16) |
         (unsigned int)(unsigned short)f2b(lo);
}

// fixed-point scale 2^40 (deterministic i64 aggregation)
#define FIXSCALE 1.0995116277760e12f
#define FIXINV   9.094947017729282e-13

// ---------------------------------------------------------------------------
// Prep (all bf16): same layouts as round 9.
// ---------------------------------------------------------------------------
__global__ void prep_kernel(const float* __restrict__ W1, const float* __restrict__ W2,
                            const float* __restrict__ b2,
                            const float* __restrict__ dW1, const float* __restrict__ dW2,
                            short* __restrict__ W1c, short* __restrict__ W2p,
                            unsigned int* __restrict__ b2pp,
                            short* __restrict__ dW1c, short* __restrict__ dW2p) {
  int t = blockIdx.x * blockDim.x + threadIdx.x;
  if (t < 64 * 32) { int c = t / 32, k = t % 32; W1c[t] = f2b(W1[k * 64 + c]); }
  if (t < 8192) {
    int ct2 = t >> 10, kt = (t >> 9) & 1, lh = (t >> 7) & 3, r = (t >> 3) & 15, j = t & 7;
    int k = (kt * 2 + (j >> 2)) * 16 + lh * 4 + (j & 3);
    int i = 2 * ct2 + ((r >> 1) & 1);
    int o = 2 * (r >> 2) + (r & 1);
    W2p[t] = f2b(W2[k * 128 + i * 8 + o]);
  }
  if (t < 64) {
    int lh = t >> 4, slot = t & 15;
    int ct2 = slot >> 1, ih = slot & 1;
    int i = 2 * ct2 + ih;
    unsigned int lo = (unsigned short)f2b(b2[i * 8 + 2 * lh]);
    unsigned int hi = (unsigned short)f2b(b2[i * 8 + 2 * lh + 1]);
    b2pp[t] = (hi << 16) | lo;
  }
  if (t < 64 * 16) { int c = t / 16, k = t % 16; dW1c[t] = f2b(dW1[k * 64 + c]); }
  if (t < 2048) {
    int ct2 = t >> 10, kt = (t >> 9) & 1, lh = (t >> 7) & 3, r = (t >> 3) & 15, j = t & 7;
    int k = (kt * 2 + (j >> 2)) * 16 + lh * 4 + (j & 3);
    dW2p[t] = f2b(dW2[k * 32 + ct2 * 16 + r]);
  }
}

// ---------------------------------------------------------------------------
// Bucket histogram (782 bins, LDS-staged) + single-block exclusive scan
// ---------------------------------------------------------------------------
__global__ __launch_bounds__(256) void bhist_kernel(const int* __restrict__ ei,
                                                    int* __restrict__ bins,
                                                    int E, int nbuck) {
  __shared__ int h[1024];
  for (int i = threadIdx.x; i < nbuck; i += 256) h[i] = 0;
  __syncthreads();
  for (int e = blockIdx.x * blockDim.x + threadIdx.x; e < E; e += gridDim.x * blockDim.x)
    atomicAdd(&h[ei[E + e] >> BSHIFT], 1);
  __syncthreads();
  for (int i = threadIdx.x; i < nbuck; i += 256)
    if (h[i]) atomicAdd(&bins[i], h[i]);
}

__global__ __launch_bounds__(1024) void bscan_kernel(const int* __restrict__ bins,
                                                     int* __restrict__ bases,
                                                     int* __restrict__ cursor, int nbuck) {
  __shared__ int sh[1024];
  int tid = threadIdx.x;
  int v = (tid < nbuck) ? bins[tid] : 0;
  sh[tid] = v;
  __syncthreads();
  for (int off = 1; off < 1024; off <<= 1) {
    int t = (tid >= off) ? sh[tid - off] : 0;
    __syncthreads();
    sh[tid] += t;
    __syncthreads();
  }
  int ex = sh[tid] - v;
  if (tid < nbuck) { bases[tid] = ex; cursor[tid] = ex; }
  if (tid == 0) bases[nbuck] = sh[1023];
}

// ---------------------------------------------------------------------------
// Partition: block processes PCHUNK edges; LDS hist -> one global claim per
// (block,bucket) -> records written into per-block contiguous runs (same-XCD
// L2 write merging => line-dense write-back). rec = (eid<<7)|(tgt&127).
// ---------------------------------------------------------------------------
__global__ __launch_bounds__(256) void part_kernel(const int* __restrict__ ei,
                                                   int* __restrict__ cursor,
                                                   unsigned int* __restrict__ recs,
                                                   int E, int nbuck) {
  __shared__ int h[1024];
  __shared__ int gcl[1024];
  __shared__ int lr[1024];
  const int tid  = threadIdx.x;
  const int base = blockIdx.x * PCHUNK;

  for (int i = tid; i < nbuck; i += 256) { h[i] = 0; lr[i] = 0; }
  __syncthreads();
  for (int i = tid; i < PCHUNK; i += 256) {
    int e = base + i;
    if (e < E) atomicAdd(&h[ei[E + e] >> BSHIFT], 1);
  }
  __syncthreads();
  for (int i = tid; i < nbuck; i += 256)
    gcl[i] = h[i] ? atomicAdd(&cursor[i], h[i]) : 0;
  __syncthreads();
  for (int i = tid; i < PCHUNK; i += 256) {
    int e = base + i;
    if (e >= E) continue;
    int tgt = ei[E + e];
    int b = tgt >> BSHIFT;
    int p = gcl[b] + atomicAdd(&lr[b], 1);
    recs[p] = ((unsigned int)e << BSHIFT) | (unsigned int)(tgt & (BNODES - 1));
  }
}

// ---------------------------------------------------------------------------
// Encoder: weights LDS-staged, attr prefetched, EDGE-ORDER coalesced bf16
// message store (no atomics, no scatter).
// ---------------------------------------------------------------------------
__global__ __launch_bounds__(256, 3) void enc_mfma_kernel(
    const int* __restrict__ ei, const float* __restrict__ attr,
    const float* __restrict__ emb,
    const short* __restrict__ W1c, const float* __restrict__ b1,
    const short* __restrict__ W2p, const unsigned int* __restrict__ b2pp,
    short* __restrict__ ms, int E) {
  __shared__ short lds_w1[2048];          // [64 hid][32 k]
  __shared__ short lds_w2[8192];          // GEMM2' fragments
  __shared__ float lds_b1[64];
  __shared__ unsigned int lds_b2[64];

  const int tid = threadIdx.x;
  const int w = tid >> 6, l = tid & 63;
  const int lh = l >> 4, ll = l & 15;
  const int ebase = blockIdx.x * 256 + w * 64;

  // cooperative weight staging (coalesced 16B per thread)
  {
    reinterpret_cast<int4*>(lds_w1)[tid] = reinterpret_cast<const int4*>(W1c)[tid];
#pragma unroll
    for (int i = 0; i < 4; i++)
      reinterpret_cast<int4*>(lds_w2)[i * 256 + tid] =
          reinterpret_cast<const int4*>(W2p)[i * 256 + tid];
    if (tid < 64) lds_b1[tid] = b1[tid];
    if (tid < 64) lds_b2[tid] = b2pp[tid];
  }

  // phase 0: gather src embedding, pack to bf16 pairs
  unsigned int xqp[8];
  {
    int ec = min(ebase + l, E - 1);
    int src = ei[ec];
    const float4* er = reinterpret_cast<const float4*>(emb) + (size_t)src * 4;
    float4 v0 = er[0], v1 = er[1], v2 = er[2], v3 = er[3];
    xqp[0] = pk2(v0.x, v0.y); xqp[1] = pk2(v0.z, v0.w);
    xqp[2] = pk2(v1.x, v1.y); xqp[3] = pk2(v1.z, v1.w);
    xqp[4] = pk2(v2.x, v2.y); xqp[5] = pk2(v2.z, v2.w);
    xqp[6] = pk2(v3.x, v3.y); xqp[7] = pk2(v3.z, v3.w);
  }

  // prefetch attr rows for all 4 tiles, convert to bf16 fragments (16 regs)
  s16x8 afs[4];
#pragma unroll
  for (int mt = 0; mt < 4; mt++) {
    int rowA = min(ebase + mt * 16 + ll, E - 1);
    const float4* ap = reinterpret_cast<const float4*>(attr + (size_t)rowA * EDIM + lh * 8);
    float4 a0 = ap[0], a1 = ap[1];
    afs[mt][0]=f2b(a0.x); afs[mt][1]=f2b(a0.y); afs[mt][2]=f2b(a0.z); afs[mt][3]=f2b(a0.w);
    afs[mt][4]=f2b(a1.x); afs[mt][5]=f2b(a1.y); afs[mt][6]=f2b(a1.z); afs[mt][7]=f2b(a1.w);
  }

  __syncthreads();

  const f32x4 z = {0.f, 0.f, 0.f, 0.f};

#pragma unroll
  for (int mt = 0; mt < 4; mt++) {
    // GEMM1' -> H^T fragments (weights streamed from LDS)
    f32x4 c1t[4];
#pragma unroll
    for (int ct = 0; ct < 4; ct++) {
      s16x8 b1f = *reinterpret_cast<const s16x8*>(lds_w1 + (ct * 16 + ll) * 32 + lh * 8);
      c1t[ct] = __builtin_amdgcn_mfma_f32_16x16x32_bf16(b1f, afs[mt], z, 0, 0, 0);
    }

    short hb[4][4];
#pragma unroll
    for (int ct = 0; ct < 4; ct++) {
      float4 bv = *reinterpret_cast<const float4*>(lds_b1 + ct * 16 + lh * 4);  // broadcast
      hb[ct][0] = f2b(fmaxf(c1t[ct][0] + bv.x, 0.f));
      hb[ct][1] = f2b(fmaxf(c1t[ct][1] + bv.y, 0.f));
      hb[ct][2] = f2b(fmaxf(c1t[ct][2] + bv.z, 0.f));
      hb[ct][3] = f2b(fmaxf(c1t[ct][3] + bv.w, 0.f));
    }
    s16x8 a2f0, a2f1;
#pragma unroll
    for (int j = 0; j < 8; j++) a2f0[j] = hb[(j >> 2)][j & 3];
#pragma unroll
    for (int j = 0; j < 8; j++) a2f1[j] = hb[2 + (j >> 2)][j & 3];

    // fetch xe pairs of edge mt*16+ll (from the owning lane)
    const int srcl = mt * 16 + ll;
    unsigned int xs[8];
#pragma unroll
    for (int c = 0; c < 8; c++)
      xs[c] = (unsigned int)__shfl((int)xqp[c], srcl, 64);

    // GEMM2' + lane-local epilogue with bias (weights + bias from LDS)
    float q0 = 0.f, q1 = 0.f;
#pragma unroll
    for (int ct2 = 0; ct2 < 8; ct2++) {
      s16x8 f0 = *reinterpret_cast<const s16x8*>(lds_w2 + ((ct2 * 2 + 0) * 4 + lh) * 128 + ll * 8);
      s16x8 f1 = *reinterpret_cast<const s16x8*>(lds_w2 + ((ct2 * 2 + 1) * 4 + lh) * 128 + ll * 8);
      f32x4 c2 = __builtin_amdgcn_mfma_f32_16x16x32_bf16(f0, a2f0, z, 0, 0, 0);
      c2 = __builtin_amdgcn_mfma_f32_16x16x32_bf16(f1, a2f1, c2, 0, 0, 0);
      uint2 pp = *reinterpret_cast<const uint2*>(lds_b2 + lh * 16 + 2 * ct2);  // broadcast
      float b00 = asf(pp.x << 16), b01 = asf(pp.x & 0xffff0000u);
      float b10 = asf(pp.y << 16), b11 = asf(pp.y & 0xffff0000u);
      float xv0 = asf(xs[ct2] << 16);          // xe[2*ct2]
      float xv1 = asf(xs[ct2] & 0xffff0000u);  // xe[2*ct2+1]
      q0 = fmaf(xv0, c2[0] + b00, q0);
      q1 = fmaf(xv0, c2[1] + b01, q1);
      q0 = fmaf(xv1, c2[2] + b10, q0);
      q1 = fmaf(xv1, c2[3] + b11, q1);
    }
    // coalesced bf16 store in EDGE order
    int e = ebase + mt * 16 + ll;
    if (e < E)
      *reinterpret_cast<unsigned int*>(ms + (size_t)e * LAT + 2 * lh) = pk2(q0, q1);
  }
}

// ---------------------------------------------------------------------------
// Aggregate: one block per bucket. Contiguous record read, random ms gather
// (L3-resident), deterministic i64 fixed-point LDS accumulation, then
// mean + conv_b + node_emb@rootW -> latent (coalesced).
// ---------------------------------------------------------------------------
__global__ __launch_bounds__(256) void agg_kernel(
    const float* __restrict__ emb, const short* __restrict__ ms,
    const unsigned int* __restrict__ recs, const int* __restrict__ bases,
    const float* __restrict__ rootW, const float* __restrict__ convb,
    float* __restrict__ latent, int N) {
  __shared__ long long acc[BNODES][LAT];   // 8 KB
  __shared__ int cnt[BNODES];
  __shared__ float rw[EMB * LAT];          // 512 B
  __shared__ float cb[LAT];

  const int tid = threadIdx.x;
  const int b = blockIdx.x;

  long long* af = &acc[0][0];
  for (int i = tid; i < BNODES * LAT; i += 256) af[i] = 0;
  if (tid < BNODES) cnt[tid] = 0;
  if (tid < EMB * LAT) rw[tid] = rootW[tid];
  if (tid < LAT) cb[tid] = convb[tid];
  __syncthreads();

  const int s = bases[b], epos = bases[b + 1];
  const uint4* mp = reinterpret_cast<const uint4*>(ms);
  for (int i = s + tid; i < epos; i += 256) {
    unsigned int r = recs[i];
    int eid = (int)(r >> BSHIFT);
    int tl  = (int)(r & (BNODES - 1));
    uint4 m = mp[(size_t)eid];
    float f0 = asf(m.x << 16), f1 = asf(m.x & 0xffff0000u);
    float f2 = asf(m.y << 16), f3 = asf(m.y & 0xffff0000u);
    float f4 = asf(m.z << 16), f5 = asf(m.z & 0xffff0000u);
    float f6 = asf(m.w << 16), f7 = asf(m.w & 0xffff0000u);
    atomicAdd((unsigned long long*)&acc[tl][0], (unsigned long long)(long long)(f0 * FIXSCALE));
    atomicAdd((unsigned long long*)&acc[tl][1], (unsigned long long)(long long)(f1 * FIXSCALE));
    atomicAdd((unsigned long long*)&acc[tl][2], (unsigned long long)(long long)(f2 * FIXSCALE));
    atomicAdd((unsigned long long*)&acc[tl][3], (unsigned long long)(long long)(f3 * FIXSCALE));
    atomicAdd((unsigned long long*)&acc[tl][4], (unsigned long long)(long long)(f4 * FIXSCALE));
    atomicAdd((unsigned long long*)&acc[tl][5], (unsigned long long)(long long)(f5 * FIXSCALE));
    atomicAdd((unsigned long long*)&acc[tl][6], (unsigned long long)(long long)(f6 * FIXSCALE));
    atomicAdd((unsigned long long*)&acc[tl][7], (unsigned long long)(long long)(f7 * FIXSCALE));
    atomicAdd(&cnt[tl], 1);
  }
  __syncthreads();

  int n = b * BNODES + tid;
  if (tid < BNODES && n < N) {
    float inv = 1.f / fmaxf((float)cnt[tid], 1.f);
    float r[LAT];
#pragma unroll
    for (int o = 0; o < LAT; o++)
      r[o] = fmaf((float)((double)acc[tid][o] * FIXINV), inv, cb[o]);

    float x[EMB];
    const float4* np4 = reinterpret_cast<const float4*>(emb) + (size_t)n * (EMB / 4);
#pragma unroll
    for (int i = 0; i < EMB / 4; i++) {
      float4 v = np4[i];
      x[4 * i + 0] = v.x; x[4 * i + 1] = v.y; x[4 * i + 2] = v.z; x[4 * i + 3] = v.w;
    }
#pragma unroll
    for (int i = 0; i < EMB; i++)
#pragma unroll
      for (int o = 0; o < LAT; o++) r[o] = fmaf(x[i], rw[i * LAT + o], r[o]);

    float4* lp = reinterpret_cast<float4*>(latent) + (size_t)n * 2;
    lp[0] = make_float4(r[0], r[1], r[2], r[3]);
    lp[1] = make_float4(r[4], r[5], r[6], r[7]);
  }
}

// ---------------------------------------------------------------------------
// Decoder: unchanged from round 9 (weights LDS-staged, K-pad zeros, per-mt
// latent gather, transposed GEMM2 -> coalesced float4 stores).
// ---------------------------------------------------------------------------
__global__ __launch_bounds__(256, 4) void dec_mfma_kernel(
    const int* __restrict__ ei, const float* __restrict__ lat,
    const short* __restrict__ dW1c, const float* __restrict__ db1,
    const short* __restrict__ dW2p, const float* __restrict__ db2,
    float* __restrict__ out, int E) {
  __shared__ short lds_w1[2048];   // [64 hid][32 k], k>=16 zeroed
  __shared__ short lds_w2[2048];   // dec GEMM2' fragments
  __shared__ float lds_b1[64];
  __shared__ float lds_b2[32];

  const int tid = threadIdx.x;
  const int w = tid >> 6, l = tid & 63;
  const int lh = l >> 4, ll = l & 15;
  const int ebase = blockIdx.x * 256 + w * 64;

  {
    if (tid < 128) {
      int4 v = reinterpret_cast<const int4*>(dW1c)[tid];
      int hid = tid >> 1, kb = (tid & 1) * 8;
      *reinterpret_cast<int4*>(lds_w1 + hid * 32 + kb) = v;
      *reinterpret_cast<int4*>(lds_w1 + hid * 32 + 16 + kb) = make_int4(0, 0, 0, 0);
    }
    reinterpret_cast<int4*>(lds_w2)[tid] = reinterpret_cast<const int4*>(dW2p)[tid];
    if (tid < 64) lds_b1[tid] = db1[tid];
    if (tid < 32) lds_b2[tid] = db2[tid];
  }
  __syncthreads();

  const f32x4 z = {0.f, 0.f, 0.f, 0.f};

#pragma unroll
  for (int mt = 0; mt < 4; mt++) {
    s16x8 af = (s16x8){0, 0, 0, 0, 0, 0, 0, 0};
    if (lh < 2) {
      int rowA = min(ebase + mt * 16 + ll, E - 1);
      int node = ei[(lh == 0 ? 0 : E) + rowA];
      const float4* lp = reinterpret_cast<const float4*>(lat + (size_t)node * LAT);
      float4 p0 = lp[0], p1 = lp[1];
      af[0]=f2b(p0.x); af[1]=f2b(p0.y); af[2]=f2b(p0.z); af[3]=f2b(p0.w);
      af[4]=f2b(p1.x); af[5]=f2b(p1.y); af[6]=f2b(p1.z); af[7]=f2b(p1.w);
    }

    f32x4 c1t[4];
#pragma unroll
    for (int ct = 0; ct < 4; ct++) {
      s16x8 b1f = *reinterpret_cast<const s16x8*>(lds_w1 + (ct * 16 + ll) * 32 + lh * 8);
      c1t[ct] = __builtin_amdgcn_mfma_f32_16x16x32_bf16(b1f, af, z, 0, 0, 0);
    }

    short hb[4][4];
#pragma unroll
    for (int ct = 0; ct < 4; ct++) {
      float4 bv = *reinterpret_cast<const float4*>(lds_b1 + ct * 16 + lh * 4);  // broadcast
      hb[ct][0] = f2b(fmaxf(c1t[ct][0] + bv.x, 0.f));
      hb[ct][1] = f2b(fmaxf(c1t[ct][1] + bv.y, 0.f));
      hb[ct][2] = f2b(fmaxf(c1t[ct][2] + bv.z, 0.f));
      hb[ct][3] = f2b(fmaxf(c1t[ct][3] + bv.w, 0.f));
    }
    s16x8 a2f0, a2f1;
#pragma unroll
    for (int j = 0; j < 8; j++) a2f0[j] = hb[(j >> 2)][j & 3];
#pragma unroll
    for (int j = 0; j < 8; j++) a2f1[j] = hb[2 + (j >> 2)][j & 3];

    int e = ebase + mt * 16 + ll;
#pragma unroll
    for (int ct2 = 0; ct2 < 2; ct2++) {
      s16x8 f0 = *reinterpret_cast<const s16x8*>(lds_w2 + ((ct2 * 2 + 0) * 4 + lh) * 128 + ll * 8);
      s16x8 f1 = *reinterpret_cast<const s16x8*>(lds_w2 + ((ct2 * 2 + 1) * 4 + lh) * 128 + ll * 8);
      f32x4 c2 = __builtin_amdgcn_mfma_f32_16x16x32_bf16(f0, a2f0, z, 0, 0, 0);
      c2 = __builtin_amdgcn_mfma_f32_16x16x32_bf16(f1, a2f1, c2, 0, 0, 0);
      float4 bv = *reinterpret_cast<const float4*>(lds_b2 + ct2 * 16 + lh * 4);  // broadcast
      if (e < E)
        *reinterpret_cast<float4*>(out + (size_t)e * EDIM + ct2 * 16 + lh * 4) =
            make_float4(c2[0] + bv.x, c2[1] + bv.y, c2[2] + bv.z, c2[3] + bv.w);
    }
  }
}

// ---------------------------------------------------------------------------
extern "C" void kernel_launch(void* const* d_in, const int* in_sizes, int n_in,
                              void* d_out, int out_size, void* d_ws, size_t ws_size,
                              hipStream_t stream) {
  const int*   ei    = (const int*)  d_in[0];
  const float* attr  = (const float*)d_in[1];
  const float* emb   = (const float*)d_in[2];
  const float* ewW1  = (const float*)d_in[3];
  const float* ewb1  = (const float*)d_in[4];
  const float* ewW2  = (const float*)d_in[5];
  const float* ewb2  = (const float*)d_in[6];
  const float* rootW = (const float*)d_in[7];
  const float* convb = (const float*)d_in[8];
  const float* dW1   = (const float*)d_in[9];
  const float* db1   = (const float*)d_in[10];
  const float* dW2   = (const float*)d_in[11];
  const float* db2   = (const float*)d_in[12];
  float* out = (float*)d_out;

  const int E     = in_sizes[0] / 2;
  const int N     = in_sizes[2] / EMB;
  const int nbuck = (N + BNODES - 1) >> BSHIFT;

  // workspace layout (weights first: 16B-aligned fragment loads)
  short* W1c  = (short*)d_ws;                   // 2048 shorts
  short* W2p  = W1c + 64 * 32;                  // 8192
  short* dW1c = W2p + 8192;                     // 1024
  short* dW2p = dW1c + 64 * 16;                 // 2048
  unsigned int* b2pp = (unsigned int*)(dW2p + 2048);  // 64 u32
  short* ms   = (short*)(b2pp + 64);            // E*8 bf16 (16B/message)
  float* lat  = (float*)(ms + (size_t)E * LAT); // N*8
  unsigned int* recs = (unsigned int*)(lat + (size_t)N * LAT);  // E
  int* bins   = (int*)(recs + E);               // nbuck
  int* bases  = bins + nbuck;                   // nbuck+1
  int* cursor = bases + nbuck + 1;              // nbuck

  const int blocks_e = (E + 255) / 256;
  const int blocks_p = (E + PCHUNK - 1) / PCHUNK;

  hipMemsetAsync(bins, 0, (size_t)nbuck * sizeof(int), stream);
  prep_kernel<<<32, 256, 0, stream>>>(ewW1, ewW2, ewb2, dW1, dW2,
                                      W1c, W2p, b2pp, dW1c, dW2p);
  bhist_kernel<<<256, 256, 0, stream>>>(ei, bins, E, nbuck);
  bscan_kernel<<<1, 1024, 0, stream>>>(bins, bases, cursor, nbuck);
  part_kernel<<<blocks_p, 256, 0, stream>>>(ei, cursor, recs, E, nbuck);
  enc_mfma_kernel<<<blocks_e, 256, 0, stream>>>(ei, attr, emb, W1c, ewb1, W2p, b2pp,
                                                ms, E);
  agg_kernel<<<nbuck, 256, 0, stream>>>(emb, ms, recs, bases, rootW, convb, lat, N);
  dec_mfma_kernel<<<blocks_e, 256, 0, stream>>>(ei, lat, dW1c, db1, dW2p, db2, out, E);
}